// Round 13
// baseline (2323.095 us; speedup 1.0000x reference)
//
#include <hip/hip_runtime.h>
#include <hip/hip_fp16.h>

#define NU 100000
#define NI 50000
#define NN 150000
#define DD 64
#define KK 32
#define EUI 1000000
#define EUU 500000
#define EII 500000
#define ROWS_PB 64
#define NB_UI ((EUI + 255) / 256)
#define NB_S ((EUU + EII + 255) / 256)

static inline int cdiv(long a, int b) { return (int)((a + b - 1) / b); }

__device__ __forceinline__ float rdlane(float v, int l) {
    return __int_as_float(__builtin_amdgcn_readlane(__float_as_int(v), l));
}

__device__ __forceinline__ int shard_of(int col) {
    return (col < NU) ? col / 12500 : (col - NU) / 6250;
}

// ---------------- CSR build ----------------

__global__ void k_count(const int* __restrict__ h, int* __restrict__ cnt, int E) {
    int e = blockIdx.x * blockDim.x + threadIdx.x;
    if (e < E) atomicAdd(&cnt[h[e]], 1);
}

__global__ __launch_bounds__(1024) void k_scan(const int* __restrict__ cnt,
                                               int* __restrict__ rp, int n) {
    __shared__ int wsum[16];
    __shared__ int carry_s;
    int tid = threadIdx.x;
    int lane = tid & 63, wid = tid >> 6;
    if (tid == 0) carry_s = 0;
    __syncthreads();
    for (int base = 0; base < n; base += 1024) {
        int i = base + tid;
        int v = (i < n) ? cnt[i] : 0;
        int s = v;
#pragma unroll
        for (int off = 1; off < 64; off <<= 1) {
            int t = __shfl_up(s, off, 64);
            if (lane >= off) s += t;
        }
        if (lane == 63) wsum[wid] = s;
        __syncthreads();
        int woff = 0, total = 0;
#pragma unroll
        for (int w = 0; w < 16; w++) { int ws = wsum[w]; total += ws; if (w < wid) woff += ws; }
        int carry = carry_s;
        if (i < n) rp[i] = carry + woff + (s - v);
        __syncthreads();
        if (tid == 0) carry_s = carry + total;
        __syncthreads();
    }
    if (tid == 0) rp[n] = carry_s;
}

__global__ void k_scatter(const int* __restrict__ h, const int* __restrict__ rp,
                          int* __restrict__ cur, int* __restrict__ lst, int E) {
    int e = blockIdx.x * blockDim.x + threadIdx.x;
    if (e >= E) return;
    int r = h[e];
    int p = rp[r] + atomicAdd(&cur[r], 1);
    lst[p] = e;
}

__global__ void k_dinv(const int* __restrict__ rpu, const int* __restrict__ rpi,
                       float* __restrict__ dinv) {
    int t = blockIdx.x * blockDim.x + threadIdx.x;
    if (t >= NN) return;
    int deg = (t < NU) ? rpu[t + 1] - rpu[t] : rpi[t - NU + 1] - rpi[t - NU];
    dinv[t] = deg > 0 ? rsqrtf((float)deg) : 0.0f;
}

__global__ void k_rowsum_inv(const int* __restrict__ rp, const int* __restrict__ lst,
                             const float* __restrict__ w, float* __restrict__ out, int n) {
    int r = blockIdx.x * blockDim.x + threadIdx.x;
    if (r >= n) return;
    float s = 0.f;
    int e1 = rp[r + 1];
    for (int e = rp[r]; e < e1; e++) s += w[lst[e]];
    out[r] = (s != 0.0f) ? 1.0f / s : 0.0f;
}

__global__ void k_wdiff(const float* __restrict__ W2, float* __restrict__ Wd_g,
                        float* __restrict__ Wd_t) {
    int i = blockIdx.x * blockDim.x + threadIdx.x;
    if (i >= DD * DD) return;
    Wd_g[i] = W2[i] - W2[DD * DD + i];
    Wd_t[i] = W2[2 * DD * DD + i] - W2[3 * DD * DD + i];
}

__global__ void k_init(const float* __restrict__ ue, const float* __restrict__ ie,
                       __half* __restrict__ xh, float* __restrict__ acc) {
    size_t i = (size_t)blockIdx.x * blockDim.x + threadIdx.x;
    if (i >= (size_t)NN * DD) return;
    float v = (i < (size_t)NU * DD) ? ue[i] : ie[i - (size_t)NU * DD];
    xh[i] = __float2half(v);
    acc[i] = v;
}

// ---------------- map-building kernels (x-independent, run once) ----------------

__global__ void k_posU(const int* __restrict__ lst, int* __restrict__ pos, int E) {
    int p = blockIdx.x * blockDim.x + threadIdx.x;
    if (p < E) pos[lst[p]] = p;
}

__global__ void k_mapUI(const int* __restrict__ lst_i, const int* __restrict__ posU,
                        int* __restrict__ mUI, int E) {
    int p = blockIdx.x * blockDim.x + threadIdx.x;
    if (p < E) mUI[p] = posU[lst_i[p]];
}

__global__ void k_build_ui(const int* __restrict__ lst_u, const int* __restrict__ ui_u,
                           const int* __restrict__ ui_i, int* __restrict__ headU,
                           int* __restrict__ colUI, int E) {
    int p = blockIdx.x * blockDim.x + threadIdx.x;
    if (p >= E) return;
    int e = lst_u[p];
    headU[p] = ui_u[e];
    colUI[p] = ui_i[e] + NU;
}

__global__ void k_build_colI(const int* __restrict__ lst_i, const int* __restrict__ ui_u,
                             int* __restrict__ colUI, int E) {
    int p = blockIdx.x * blockDim.x + threadIdx.x;
    if (p < E) colUI[EUI + p] = ui_u[lst_i[p]];
}

__global__ void k_build_rp2(const int* __restrict__ rp_u, const int* __restrict__ rp_i,
                            const int* __restrict__ rp_uu, const int* __restrict__ rp_ii,
                            int* __restrict__ rp_ui, int* __restrict__ rp_s) {
    int t = blockIdx.x * blockDim.x + threadIdx.x;
    if (t > NN) return;
    rp_ui[t] = (t <= NU) ? rp_u[t] : rp_i[t - NU] + EUI;
    rp_s[t]  = (t <= NU) ? rp_uu[t] : rp_ii[t - NU] + EUU;
}

__global__ void k_build_gw(const int* __restrict__ rp, const int* __restrict__ col,
                           const float* __restrict__ dinv, float* __restrict__ gw, int n) {
    int r = blockIdx.x * blockDim.x + threadIdx.x;
    if (r >= n) return;
    float dh = dinv[r];
    int e1 = rp[r + 1];
    for (int p = rp[r]; p < e1; p++) gw[p] = dh * dinv[col[p]];
}

__global__ void k_build_s(const int* __restrict__ lst, const int* __restrict__ eh,
                          const int* __restrict__ et, const float* __restrict__ ew,
                          const float* __restrict__ inv, int off, int peo,
                          int* __restrict__ head, int* __restrict__ col,
                          float* __restrict__ bw, int E) {
    int p = blockIdx.x * blockDim.x + threadIdx.x;
    if (p >= E) return;
    int e = lst[p];
    int h = eh[e];
    head[peo + p] = h + off;
    col[peo + p] = et[e] + off;
    bw[peo + p] = ew[e] * inv[h];
}

// ---------------- tail-shard stable sort (build-time) ----------------

// per-block shard counts, column-major by shard: cntmat[sh * NB + b]
__global__ __launch_bounds__(256) void k_cntmat(const int* __restrict__ col,
                                                int* __restrict__ cntmat, int NB, int E) {
    __shared__ int lc[8];
    if (threadIdx.x < 8) lc[threadIdx.x] = 0;
    __syncthreads();
    int p = blockIdx.x * 256 + threadIdx.x;
    if (p < E) atomicAdd(&lc[shard_of(col[p])], 1);
    __syncthreads();
    if (threadIdx.x < 8) cntmat[threadIdx.x * NB + blockIdx.x] = lc[threadIdx.x];
}

// stable scatter into shard-sorted arrays; tpos keeps original CSR position
__global__ __launch_bounds__(256) void k_scatmat(
        const int* __restrict__ head, const int* __restrict__ col,
        const int* __restrict__ sc, int NB, int E,
        int* __restrict__ head2, int* __restrict__ col2, int* __restrict__ tpos) {
    __shared__ int sbase[8];
    __shared__ int wcnt[4][8];
    int tid = threadIdx.x, lane = tid & 63, w = tid >> 6;
    if (tid < 8) sbase[tid] = sc[tid * NB + blockIdx.x];
    int p = blockIdx.x * 256 + tid;
    int sh = -1, h = 0, c = 0;
    if (p < E) { h = head[p]; c = col[p]; sh = shard_of(c); }
    int rank = 0;
#pragma unroll
    for (int s = 0; s < 8; s++) {
        unsigned long long m = __ballot(sh == s);
        if (sh == s) rank = __popcll(m & ((1ull << lane) - 1ull));
        if (lane == 0) wcnt[w][s] = __popcll(m);
    }
    __syncthreads();
    if (sh >= 0) {
        int off = 0;
#pragma unroll
        for (int w2 = 0; w2 < 4; w2++) if (w2 < w) off += wcnt[w2][sh];
        int pos = sbase[sh] + off + rank;
        head2[pos] = h;
        col2[pos] = c;
        tpos[pos] = p;
    }
}

// ---------------- pass A (shard order): c[tpos[p2]] = alpha * dist, fp16 ---------------
// block b -> shard b&7; under bid%8->XCD mapping each XCD's tail reads stay L2-resident.

__global__ __launch_bounds__(256) void k_passA_sh(
        const int* __restrict__ head2, const int* __restrict__ col2,
        const int* __restrict__ tpos, const int* __restrict__ sc, int NB, int E,
        const __half* __restrict__ x, const float* __restrict__ intents,
        __half* __restrict__ c_out) {
    __shared__ float Wl[DD * KK];
    for (int idx = threadIdx.x; idx < DD * KK; idx += blockDim.x) Wl[idx] = intents[idx];
    __syncthreads();
    int sh = blockIdx.x & 7;
    int nchunk = gridDim.x >> 3;
    int chunk0 = blockIdx.x >> 3;
    int s0 = sc[sh * NB];
    int s1 = sc[(sh + 1) * NB];
    for (int base = s0 + chunk0 * 256; base < s1; base += nchunk * 256) {
        int p2 = base + threadIdx.x;
        if (p2 >= s1) continue;
        const uint4* hp = (const uint4*)(x + (size_t)head2[p2] * DD);
        const uint4* tp = (const uint4*)(x + (size_t)col2[p2] * DD);
        uint4 hraw[8], traw[8];
#pragma unroll
        for (int j = 0; j < 8; j++) hraw[j] = hp[j];
#pragma unroll
        for (int j = 0; j < 8; j++) traw[j] = tp[j];
        const __half2* h2 = (const __half2*)hraw;
        const __half2* t2 = (const __half2*)traw;
        float logit[KK];
#pragma unroll
        for (int k = 0; k < KK; k++) logit[k] = 0.f;
        float dot = 0.f;
#pragma unroll 4
        for (int l4 = 0; l4 < 16; l4++) {
            float2 ha = __half22float2(h2[2 * l4]), hb = __half22float2(h2[2 * l4 + 1]);
            float2 ta = __half22float2(t2[2 * l4]), tb = __half22float2(t2[2 * l4 + 1]);
            float p0 = ha.x * ta.x, p1 = ha.y * ta.y, p2f = hb.x * tb.x, p3 = hb.y * tb.y;
            dot += p0 + p1 + p2f + p3;
            const float* w = &Wl[l4 * 4 * KK];
#pragma unroll
            for (int k = 0; k < KK; k++)
                logit[k] += p0 * w[k] + p1 * w[KK + k] + p2f * w[2 * KK + k] + p3 * w[3 * KK + k];
        }
        float m = logit[0];
#pragma unroll
        for (int k = 1; k < KK; k++) m = fmaxf(m, logit[k]);
        float ssum = 0.f;
#pragma unroll
        for (int k = 0; k < KK; k++) { float ev = __expf(logit[k] - m); logit[k] = ev; ssum += ev; }
        float scale = 0.5f * (dot + 1.0f) / ssum;
        uint4 pk[4];
        unsigned int* u = (unsigned int*)pk;
#pragma unroll
        for (int k2 = 0; k2 < 16; k2++) {
            __half2 hh = __floats2half2_rn(logit[2 * k2] * scale, logit[2 * k2 + 1] * scale);
            u[k2] = *reinterpret_cast<const unsigned int*>(&hh);
        }
        uint4* dst = (uint4*)(c_out + (size_t)tpos[p2] * KK);
#pragma unroll
        for (int q = 0; q < 4; q++) dst[q] = pk[q];
    }
}

// readlane-based broadcast of packed component (l compile-time)
#define PRD(a0, a1, a2, a3, l) \
    rdlane(((l) & 3) == 0 ? (a0) : ((l) & 3) == 1 ? (a1) : ((l) & 3) == 2 ? (a2) : (a3), (l) >> 2)

// ---------------- fused UI: inline agg + g1 + t1 + z-preact; 64 rows/block --------------
__global__ __launch_bounds__(512) void k_fused_ui(
        const int* __restrict__ rp, const int* __restrict__ col,
        const float* __restrict__ gw, const __half* __restrict__ cbuf,
        const int* __restrict__ mUI,
        const float* __restrict__ Wd_g, const float* __restrict__ Wd_t,
        const float* __restrict__ b2, const __half* __restrict__ x,
        __half* __restrict__ gs, __half* __restrict__ ts,
        float* __restrict__ zp, int nrows) {
    __shared__ float Wg[DD * DD];
    __shared__ float Wt[DD * DD];
    for (int i = threadIdx.x; i < DD * DD; i += 512) { Wg[i] = Wd_g[i]; Wt[i] = Wd_t[i]; }
    __syncthreads();
    int wid = threadIdx.x >> 6, lane = threadIdx.x & 63;
    int sub = lane & 15, grp = lane >> 4;
    float b2v = b2[lane];
    const uint2* xq = (const uint2*)x;
    const unsigned int* cu = (const unsigned int*)cbuf;
    int rbase = blockIdx.x * ROWS_PB + wid * 8;
    for (int rr = 0; rr < 8; rr++) {
        int r = rbase + rr;
        if (r >= nrows) break;
        bool item = (r >= NU);
        int e0 = rp[r], e1 = rp[r + 1];
        float a0 = 0.f, a1 = 0.f;
        for (int e = e0; e < e1; e += 4) {
            int idx = e + grp;
            if (idx < e1) {
                int ci = item ? mUI[idx - EUI] : idx;
                unsigned int cv = cu[(size_t)ci * 16 + sub];
                float2 cf = __half22float2(*(const __half2*)&cv);
                a0 += cf.x; a1 += cf.y;
            }
        }
        a0 += __shfl_xor(a0, 16, 64); a0 += __shfl_xor(a0, 32, 64);
        a1 += __shfl_xor(a1, 16, 64); a1 += __shfl_xor(a1, 32, 64);
        float2 rc;
        rc.x = (a0 != 0.f) ? 1.f / a0 : 0.f;
        rc.y = (a1 != 0.f) ? 1.f / a1 : 0.f;
        float g0 = 0, g1 = 0, g2 = 0, g3 = 0, t0 = 0, t1 = 0, t2 = 0, t3 = 0;
        float rsacc = 0.f;
        int e = e0;
        for (; e + 8 <= e1; e += 8) {
#pragma unroll
            for (int u = 0; u < 2; u++) {
                int idx = e + 4 * u + grp;
                int cc = col[idx];
                float wg = gw[idx];
                int ci = item ? mUI[idx - EUI] : idx;
                unsigned int cv = cu[(size_t)ci * 16 + sub];
                float2 cf = __half22float2(*(const __half2*)&cv);
                float pd = fmaf(cf.x, rc.x, cf.y * rc.y);
                pd += __shfl_xor(pd, 1, 64); pd += __shfl_xor(pd, 2, 64);
                pd += __shfl_xor(pd, 4, 64); pd += __shfl_xor(pd, 8, 64);
                float wt = pd * (1.0f / KK);
                rsacc += wt;
                uint2 raw = xq[(size_t)cc * 16 + sub];
                float2 xa = __half22float2(*(const __half2*)&raw.x);
                float2 xb = __half22float2(*(const __half2*)&raw.y);
                g0 += wg * xa.x; g1 += wg * xa.y; g2 += wg * xb.x; g3 += wg * xb.y;
                t0 += wt * xa.x; t1 += wt * xa.y; t2 += wt * xb.x; t3 += wt * xb.y;
            }
        }
        for (; e < e1; e += 4) {
            int idx = e + grp;
            if (idx < e1) {
                int cc = col[idx];
                float wg = gw[idx];
                int ci = item ? mUI[idx - EUI] : idx;
                unsigned int cv = cu[(size_t)ci * 16 + sub];
                float2 cf = __half22float2(*(const __half2*)&cv);
                float pd = fmaf(cf.x, rc.x, cf.y * rc.y);
                pd += __shfl_xor(pd, 1, 64); pd += __shfl_xor(pd, 2, 64);
                pd += __shfl_xor(pd, 4, 64); pd += __shfl_xor(pd, 8, 64);
                float wt = pd * (1.0f / KK);
                rsacc += wt;
                uint2 raw = xq[(size_t)cc * 16 + sub];
                float2 xa = __half22float2(*(const __half2*)&raw.x);
                float2 xb = __half22float2(*(const __half2*)&raw.y);
                g0 += wg * xa.x; g1 += wg * xa.y; g2 += wg * xb.x; g3 += wg * xb.y;
                t0 += wt * xa.x; t1 += wt * xa.y; t2 += wt * xb.x; t3 += wt * xb.y;
            }
        }
#pragma unroll
        for (int off = 16; off <= 32; off <<= 1) {
            g0 += __shfl_xor(g0, off, 64); g1 += __shfl_xor(g1, off, 64);
            g2 += __shfl_xor(g2, off, 64); g3 += __shfl_xor(g3, off, 64);
            t0 += __shfl_xor(t0, off, 64); t1 += __shfl_xor(t1, off, 64);
            t2 += __shfl_xor(t2, off, 64); t3 += __shfl_xor(t3, off, 64);
            rsacc += __shfl_xor(rsacc, off, 64);
        }
        float rsv = (rsacc != 0.f) ? 1.0f / rsacc : 0.f;
        t0 *= rsv; t1 *= rsv; t2 *= rsv; t3 *= rsv;
        float ss = t0 * t0 + t1 * t1 + t2 * t2 + t3 * t3;
        ss += __shfl_xor(ss, 1, 64); ss += __shfl_xor(ss, 2, 64);
        ss += __shfl_xor(ss, 4, 64); ss += __shfl_xor(ss, 8, 64);
        float inv_n = 1.0f / fmaxf(sqrtf(ss), 1e-12f);
        t0 *= inv_n; t1 *= inv_n; t2 *= inv_n; t3 *= inv_n;
        float zv = b2v;
#pragma unroll
        for (int l = 0; l < DD; l++) {
            float gl = PRD(g0, g1, g2, g3, l);
            float tl = PRD(t0, t1, t2, t3, l);
            zv += gl * Wg[l * DD + lane] + tl * Wt[l * DD + lane];
        }
        float ga0 = __shfl(g0, lane >> 2, 64), ga1 = __shfl(g1, lane >> 2, 64);
        float ga2 = __shfl(g2, lane >> 2, 64), ga3 = __shfl(g3, lane >> 2, 64);
        float ta0 = __shfl(t0, lane >> 2, 64), ta1 = __shfl(t1, lane >> 2, 64);
        float ta2 = __shfl(t2, lane >> 2, 64), ta3 = __shfl(t3, lane >> 2, 64);
        int j = lane & 3;
        float gsv = j == 0 ? ga0 : j == 1 ? ga1 : j == 2 ? ga2 : ga3;
        float tsv = j == 0 ? ta0 : j == 1 ? ta1 : j == 2 ? ta2 : ta3;
        size_t oi = (size_t)r * DD + lane;
        gs[oi] = __float2half(gsv);
        ts[oi] = __float2half(tsv);
        zp[oi] = zv;
    }
}

// ---------------- fused finalize: inline agg + g2 + t2 + gate + combine -----------------
__global__ __launch_bounds__(512) void k_fused_fin(
        const int* __restrict__ rp, const int* __restrict__ col,
        const float* __restrict__ bw, const __half* __restrict__ cbuf,
        const float* __restrict__ W1, const float* __restrict__ W3,
        const __half* __restrict__ x, const __half* __restrict__ gs,
        const __half* __restrict__ ts, const float* __restrict__ zp,
        __half* __restrict__ xh_out, float* __restrict__ acc, int nrows) {
    __shared__ float Wa[DD * DD];
    __shared__ float Wb[DD * DD];
    for (int i = threadIdx.x; i < DD * DD; i += 512) { Wa[i] = W1[i]; Wb[i] = W3[i]; }
    __syncthreads();
    int wid = threadIdx.x >> 6, lane = threadIdx.x & 63;
    int sub = lane & 15, grp = lane >> 4;
    const uint2* xq = (const uint2*)x;
    const unsigned int* cu = (const unsigned int*)cbuf;
    int rbase = blockIdx.x * ROWS_PB + wid * 8;
    for (int rr = 0; rr < 8; rr++) {
        int r = rbase + rr;
        if (r >= nrows) break;
        int e0 = rp[r], e1 = rp[r + 1];
        float a0 = 0.f, a1 = 0.f;
        for (int e = e0; e < e1; e += 4) {
            int idx = e + grp;
            if (idx < e1) {
                unsigned int cv = cu[(size_t)idx * 16 + sub];
                float2 cf = __half22float2(*(const __half2*)&cv);
                a0 += cf.x; a1 += cf.y;
            }
        }
        a0 += __shfl_xor(a0, 16, 64); a0 += __shfl_xor(a0, 32, 64);
        a1 += __shfl_xor(a1, 16, 64); a1 += __shfl_xor(a1, 32, 64);
        float2 rc;
        rc.x = (a0 != 0.f) ? 1.f / a0 : 0.f;
        rc.y = (a1 != 0.f) ? 1.f / a1 : 0.f;
        float g0 = 0, g1 = 0, g2 = 0, g3 = 0, t0 = 0, t1 = 0, t2 = 0, t3 = 0;
        float rsacc = 0.f;
        int e = e0;
        for (; e + 8 <= e1; e += 8) {
#pragma unroll
            for (int u = 0; u < 2; u++) {
                int idx = e + 4 * u + grp;
                int cc = col[idx];
                float wg = bw[idx];
                unsigned int cv = cu[(size_t)idx * 16 + sub];
                float2 cf = __half22float2(*(const __half2*)&cv);
                float pd = fmaf(cf.x, rc.x, cf.y * rc.y);
                pd += __shfl_xor(pd, 1, 64); pd += __shfl_xor(pd, 2, 64);
                pd += __shfl_xor(pd, 4, 64); pd += __shfl_xor(pd, 8, 64);
                float wt = pd * (1.0f / KK);
                rsacc += wt;
                uint2 raw = xq[(size_t)cc * 16 + sub];
                float2 xa = __half22float2(*(const __half2*)&raw.x);
                float2 xb = __half22float2(*(const __half2*)&raw.y);
                g0 += wg * xa.x; g1 += wg * xa.y; g2 += wg * xb.x; g3 += wg * xb.y;
                t0 += wt * xa.x; t1 += wt * xa.y; t2 += wt * xb.x; t3 += wt * xb.y;
            }
        }
        for (; e < e1; e += 4) {
            int idx = e + grp;
            if (idx < e1) {
                int cc = col[idx];
                float wg = bw[idx];
                unsigned int cv = cu[(size_t)idx * 16 + sub];
                float2 cf = __half22float2(*(const __half2*)&cv);
                float pd = fmaf(cf.x, rc.x, cf.y * rc.y);
                pd += __shfl_xor(pd, 1, 64); pd += __shfl_xor(pd, 2, 64);
                pd += __shfl_xor(pd, 4, 64); pd += __shfl_xor(pd, 8, 64);
                float wt = pd * (1.0f / KK);
                rsacc += wt;
                uint2 raw = xq[(size_t)cc * 16 + sub];
                float2 xa = __half22float2(*(const __half2*)&raw.x);
                float2 xb = __half22float2(*(const __half2*)&raw.y);
                g0 += wg * xa.x; g1 += wg * xa.y; g2 += wg * xb.x; g3 += wg * xb.y;
                t0 += wt * xa.x; t1 += wt * xa.y; t2 += wt * xb.x; t3 += wt * xb.y;
            }
        }
#pragma unroll
        for (int off = 16; off <= 32; off <<= 1) {
            g0 += __shfl_xor(g0, off, 64); g1 += __shfl_xor(g1, off, 64);
            g2 += __shfl_xor(g2, off, 64); g3 += __shfl_xor(g3, off, 64);
            t0 += __shfl_xor(t0, off, 64); t1 += __shfl_xor(t1, off, 64);
            t2 += __shfl_xor(t2, off, 64); t3 += __shfl_xor(t3, off, 64);
            rsacc += __shfl_xor(rsacc, off, 64);
        }
        float rsv = (rsacc != 0.f) ? 1.0f / rsacc : 0.f;
        t0 *= rsv; t1 *= rsv; t2 *= rsv; t3 *= rsv;
        float ss = t0 * t0 + t1 * t1 + t2 * t2 + t3 * t3;
        ss += __shfl_xor(ss, 1, 64); ss += __shfl_xor(ss, 2, 64);
        ss += __shfl_xor(ss, 4, 64); ss += __shfl_xor(ss, 8, 64);
        float inv_n = 1.0f / fmaxf(sqrtf(ss), 1e-12f);
        t0 *= inv_n; t1 *= inv_n; t2 *= inv_n; t3 *= inv_n;
        uint2 gp2 = ((const uint2*)(gs + (size_t)r * DD))[sub];
        uint2 tp2 = ((const uint2*)(ts + (size_t)r * DD))[sub];
        float2 gpa = __half22float2(*(const __half2*)&gp2.x);
        float2 gpb = __half22float2(*(const __half2*)&gp2.y);
        float2 tpa = __half22float2(*(const __half2*)&tp2.x);
        float2 tpb = __half22float2(*(const __half2*)&tp2.y);
        float gf0 = gpa.x + g0, gf1 = gpa.y + g1, gf2 = gpb.x + g2, gf3 = gpb.y + g3;
        float tf0 = tpa.x + t0, tf1 = tpa.y + t1, tf2 = tpb.x + t2, tf3 = tpb.y + t3;
        size_t oi = (size_t)r * DD + lane;
        float zv = zp[oi];
#pragma unroll
        for (int l = 0; l < DD; l++) {
            float gl = PRD(gf0, gf1, gf2, gf3, l);
            float tl = PRD(tf0, tf1, tf2, tf3, l);
            zv += gl * Wa[l * DD + lane] + tl * Wb[l * DD + lane];
        }
        float ga0 = __shfl(gf0, lane >> 2, 64), ga1 = __shfl(gf1, lane >> 2, 64);
        float ga2 = __shfl(gf2, lane >> 2, 64), ga3 = __shfl(gf3, lane >> 2, 64);
        float ta0 = __shfl(tf0, lane >> 2, 64), ta1 = __shfl(tf1, lane >> 2, 64);
        float ta2 = __shfl(tf2, lane >> 2, 64), ta3 = __shfl(tf3, lane >> 2, 64);
        int j = lane & 3;
        float gfin = j == 0 ? ga0 : j == 1 ? ga1 : j == 2 ? ga2 : ga3;
        float tfin = j == 0 ? ta0 : j == 1 ? ta1 : j == 2 ? ta2 : ta3;
        float gate = 1.0f / (1.0f + __expf(-zv));
        float xn = gate * gfin + (1.0f - gate) * tfin;
        xh_out[oi] = __float2half(xn);
        acc[oi] += xn;
    }
}

// ---------------- host launcher ----------------

extern "C" void kernel_launch(void* const* d_in, const int* in_sizes, int n_in,
                              void* d_out, int out_size, void* d_ws, size_t ws_size,
                              hipStream_t stream) {
    const float* user_emb = (const float*)d_in[0];
    const float* item_emb = (const float*)d_in[1];
    const float* intents  = (const float*)d_in[2];
    const float* W2       = (const float*)d_in[3];
    const float* b2       = (const float*)d_in[4];
    const float* uu_w     = (const float*)d_in[5];
    const float* ii_w     = (const float*)d_in[6];
    const int*   ui_u     = (const int*)d_in[7];
    const int*   ui_i     = (const int*)d_in[8];
    const int*   uu_h     = (const int*)d_in[9];
    const int*   uu_t     = (const int*)d_in[10];
    const int*   ii_h     = (const int*)d_in[11];
    const int*   ii_t     = (const int*)d_in[12];
    float* acc = (float*)d_out;

    char* pw = (char*)d_ws;
    auto allocb = [&](size_t nbytes) -> char* {
        char* r = pw;
        pw += (nbytes + 255) & ~(size_t)255;
        return r;
    };
    // ~244 MB total
    __half* gs   = (__half*)allocb((size_t)NN * DD * 2);
    __half* ts   = (__half*)allocb((size_t)NN * DD * 2);
    float* zp    = (float*)allocb((size_t)NN * DD * 4);
    __half* xh0  = (__half*)allocb((size_t)NN * DD * 2);
    __half* xh1  = (__half*)allocb((size_t)NN * DD * 2);
    __half* c    = (__half*)allocb((size_t)EUI * KK * 2);  // 64 MB; build scratch aliases here
    float* dinv  = (float*)allocb((size_t)NN * 4);
    float* iuu   = (float*)allocb((size_t)NU * 4);
    float* iii   = (float*)allocb((size_t)NI * 4);
    float* Wd_g  = (float*)allocb((size_t)DD * DD * 4);
    float* Wd_t  = (float*)allocb((size_t)DD * DD * 4);
    int* rp_u    = (int*)allocb(((size_t)NU + 1) * 4);
    int* rp_i    = (int*)allocb(((size_t)NI + 1) * 4);
    int* rp_uu   = (int*)allocb(((size_t)NU + 1) * 4);
    int* rp_ii   = (int*)allocb(((size_t)NI + 1) * 4);
    int* rp_ui   = (int*)allocb(((size_t)NN + 1) * 4);
    int* rp_s    = (int*)allocb(((size_t)NN + 1) * 4);
    int* headU   = (int*)allocb((size_t)EUI * 4);
    int* colUI   = (int*)allocb((size_t)2 * EUI * 4);
    int* head_s  = (int*)allocb((size_t)(EUU + EII) * 4);
    int* col_s   = (int*)allocb((size_t)(EUU + EII) * 4);
    float* bw_s  = (float*)allocb((size_t)(EUU + EII) * 4);
    int* mUI     = (int*)allocb((size_t)EUI * 4);
    float* gwUI  = (float*)allocb((size_t)2 * EUI * 4);
    // shard-sorted passA inputs
    int* scU     = (int*)allocb((size_t)(8 * NB_UI + 1) * 4);
    int* scS     = (int*)allocb((size_t)(8 * NB_S + 1) * 4);
    int* h2U     = (int*)allocb((size_t)EUI * 4);
    int* c2U     = (int*)allocb((size_t)EUI * 4);
    int* tpU     = (int*)allocb((size_t)EUI * 4);
    int* h2S     = (int*)allocb((size_t)(EUU + EII) * 4);
    int* c2S     = (int*)allocb((size_t)(EUU + EII) * 4);
    int* tpS     = (int*)allocb((size_t)(EUU + EII) * 4);

    char* ca = (char*)c;
    int* cur    = (int*)ca;  ca += ((size_t)NU * 4 + 255) & ~(size_t)255;
    int* lst_u  = (int*)ca;  ca += ((size_t)EUI * 4 + 255) & ~(size_t)255;
    int* lst_i  = (int*)ca;  ca += ((size_t)EUI * 4 + 255) & ~(size_t)255;
    int* lst_uu = (int*)ca;  ca += ((size_t)EUU * 4 + 255) & ~(size_t)255;
    int* lst_ii = (int*)ca;  ca += ((size_t)EII * 4 + 255) & ~(size_t)255;
    int* posU   = (int*)ca;  ca += ((size_t)EUI * 4 + 255) & ~(size_t)255;
    int* cmU    = (int*)ca;  ca += ((size_t)(8 * NB_UI) * 4 + 255) & ~(size_t)255;
    int* cmS    = (int*)ca;

    const int B = 256;

    auto build_csr = [&](const int* h, int E, int n, int* rp, int* lst) {
        hipMemsetAsync(cur, 0, (size_t)n * 4, stream);
        k_count<<<cdiv(E, B), B, 0, stream>>>(h, cur, E);
        k_scan<<<1, 1024, 0, stream>>>(cur, rp, n);
        hipMemsetAsync(cur, 0, (size_t)n * 4, stream);
        k_scatter<<<cdiv(E, B), B, 0, stream>>>(h, rp, cur, lst, E);
    };

    build_csr(ui_u, EUI, NU, rp_u, lst_u);
    build_csr(ui_i, EUI, NI, rp_i, lst_i);
    build_csr(uu_h, EUU, NU, rp_uu, lst_uu);
    build_csr(ii_h, EII, NI, rp_ii, lst_ii);
    k_dinv<<<cdiv(NN, B), B, 0, stream>>>(rp_u, rp_i, dinv);
    k_rowsum_inv<<<cdiv(NU, B), B, 0, stream>>>(rp_uu, lst_uu, uu_w, iuu, NU);
    k_rowsum_inv<<<cdiv(NI, B), B, 0, stream>>>(rp_ii, lst_ii, ii_w, iii, NI);
    k_build_rp2<<<cdiv(NN + 1, B), B, 0, stream>>>(rp_u, rp_i, rp_uu, rp_ii, rp_ui, rp_s);
    k_build_ui<<<cdiv(EUI, B), B, 0, stream>>>(lst_u, ui_u, ui_i, headU, colUI, EUI);
    k_build_colI<<<cdiv(EUI, B), B, 0, stream>>>(lst_i, ui_u, colUI, EUI);
    k_posU<<<cdiv(EUI, B), B, 0, stream>>>(lst_u, posU, EUI);
    k_mapUI<<<cdiv(EUI, B), B, 0, stream>>>(lst_i, posU, mUI, EUI);
    k_build_s<<<cdiv(EUU, B), B, 0, stream>>>(lst_uu, uu_h, uu_t, uu_w, iuu, 0, 0,
                                              head_s, col_s, bw_s, EUU);
    k_build_s<<<cdiv(EII, B), B, 0, stream>>>(lst_ii, ii_h, ii_t, ii_w, iii, NU, EUU,
                                              head_s, col_s, bw_s, EII);
    k_build_gw<<<cdiv(NN, B), B, 0, stream>>>(rp_ui, colUI, dinv, gwUI, NN);
    k_wdiff<<<cdiv(DD * DD, B), B, 0, stream>>>(W2, Wd_g, Wd_t);
    k_init<<<cdiv((long)NN * DD, B), B, 0, stream>>>(user_emb, item_emb, xh0, acc);

    // ---- tail-shard stable sort for passA (x-independent) ----
    k_cntmat<<<NB_UI, B, 0, stream>>>(colUI, cmU, NB_UI, EUI);
    k_scan<<<1, 1024, 0, stream>>>(cmU, scU, 8 * NB_UI);
    k_scatmat<<<NB_UI, B, 0, stream>>>(headU, colUI, scU, NB_UI, EUI, h2U, c2U, tpU);
    k_cntmat<<<NB_S, B, 0, stream>>>(col_s, cmS, NB_S, EUU + EII);
    k_scan<<<1, 1024, 0, stream>>>(cmS, scS, 8 * NB_S);
    k_scatmat<<<NB_S, B, 0, stream>>>(head_s, col_s, scS, NB_S, EUU + EII, h2S, c2S, tpS);

    for (int layer = 0; layer < 2; ++layer) {
        const __half* xin = (layer == 0) ? xh0 : xh1;
        __half* xout = (layer == 0) ? xh1 : xh0;

        // ---- UI phase ----
        k_passA_sh<<<2048, B, 0, stream>>>(h2U, c2U, tpU, scU, NB_UI, EUI, xin, intents, c);
        k_fused_ui<<<cdiv(NN, ROWS_PB), 512, 0, stream>>>(rp_ui, colUI, gwUI, c, mUI,
                                                          Wd_g, Wd_t, b2, xin, gs, ts, zp, NN);

        // ---- UU+II phase ----
        k_passA_sh<<<2048, B, 0, stream>>>(h2S, c2S, tpS, scS, NB_S, EUU + EII, xin, intents, c);
        k_fused_fin<<<cdiv(NN, ROWS_PB), 512, 0, stream>>>(rp_s, col_s, bw_s, c,
                                                           W2 + DD * DD, W2 + 3 * DD * DD,
                                                           xin, gs, ts, zp, xout, acc, NN);
    }
}

// Round 14
// 2294.543 us; speedup vs baseline: 1.0124x; 1.0124x over previous
//
#include <hip/hip_runtime.h>
#include <hip/hip_fp16.h>

#define NU 100000
#define NI 50000
#define NN 150000
#define DD 64
#define KK 32
#define EUI 1000000
#define EUU 500000
#define EII 500000
#define ROWS_PB 64
#define FB 2344           // cdiv(NN, ROWS_PB)
#define PB 1172           // FB / 2
#define MEGA_GRID (FB + PB)

static inline int cdiv(long a, int b) { return (int)((a + b - 1) / b); }

__device__ __forceinline__ float rdlane(float v, int l) {
    return __int_as_float(__builtin_amdgcn_readlane(__float_as_int(v), l));
}

// ---- self-consistent fp8-e4m3-style codec with x32 pre-scale ----
__device__ __forceinline__ unsigned int enc8(float f) {
    float a = fabsf(f) * 32.0f;
    unsigned int s = (__float_as_uint(f) >> 31) << 7;
    if (a < 0.015625f) return s;          // flush subnormals (c < 4.9e-4)
    if (a > 448.0f) a = 448.0f;
    unsigned int ub = __float_as_uint(a);
    ub += 0x7FFFF + ((ub >> 20) & 1);     // RNE to 3-bit mantissa
    int ex = (int)((ub >> 23) & 0xff) - 127;
    if (ex < -6) return s;
    unsigned int m = (ub >> 20) & 7;
    unsigned int e = (unsigned int)(ex + 7);
    if (e > 15) { e = 15; m = 7; }
    return s | (e << 3) | m;
}
__device__ __forceinline__ float dec8(unsigned int b) {
    unsigned int s = (b >> 7) & 1, e = (b >> 3) & 15, m = b & 7;
    if ((b & 0x7f) == 0) return 0.f;
    unsigned int ub = ((e + 120) << 23) | (m << 20) | (s << 31);
    return __uint_as_float(ub) * 0.03125f;
}

// ---------------- CSR build ----------------

__global__ void k_count(const int* __restrict__ h, int* __restrict__ cnt, int E) {
    int e = blockIdx.x * blockDim.x + threadIdx.x;
    if (e < E) atomicAdd(&cnt[h[e]], 1);
}

__global__ __launch_bounds__(1024) void k_scan(const int* __restrict__ cnt,
                                               int* __restrict__ rp, int n) {
    __shared__ int wsum[16];
    __shared__ int carry_s;
    int tid = threadIdx.x;
    int lane = tid & 63, wid = tid >> 6;
    if (tid == 0) carry_s = 0;
    __syncthreads();
    for (int base = 0; base < n; base += 1024) {
        int i = base + tid;
        int v = (i < n) ? cnt[i] : 0;
        int s = v;
#pragma unroll
        for (int off = 1; off < 64; off <<= 1) {
            int t = __shfl_up(s, off, 64);
            if (lane >= off) s += t;
        }
        if (lane == 63) wsum[wid] = s;
        __syncthreads();
        int woff = 0, total = 0;
#pragma unroll
        for (int w = 0; w < 16; w++) { int ws = wsum[w]; total += ws; if (w < wid) woff += ws; }
        int carry = carry_s;
        if (i < n) rp[i] = carry + woff + (s - v);
        __syncthreads();
        if (tid == 0) carry_s = carry + total;
        __syncthreads();
    }
    if (tid == 0) rp[n] = carry_s;
}

__global__ void k_scatter(const int* __restrict__ h, const int* __restrict__ rp,
                          int* __restrict__ cur, int* __restrict__ lst, int E) {
    int e = blockIdx.x * blockDim.x + threadIdx.x;
    if (e >= E) return;
    int r = h[e];
    int p = rp[r] + atomicAdd(&cur[r], 1);
    lst[p] = e;
}

__global__ void k_dinv(const int* __restrict__ rpu, const int* __restrict__ rpi,
                       float* __restrict__ dinv) {
    int t = blockIdx.x * blockDim.x + threadIdx.x;
    if (t >= NN) return;
    int deg = (t < NU) ? rpu[t + 1] - rpu[t] : rpi[t - NU + 1] - rpi[t - NU];
    dinv[t] = deg > 0 ? rsqrtf((float)deg) : 0.0f;
}

__global__ void k_rowsum_inv(const int* __restrict__ rp, const int* __restrict__ lst,
                             const float* __restrict__ w, float* __restrict__ out, int n) {
    int r = blockIdx.x * blockDim.x + threadIdx.x;
    if (r >= n) return;
    float s = 0.f;
    int e1 = rp[r + 1];
    for (int e = rp[r]; e < e1; e++) s += w[lst[e]];
    out[r] = (s != 0.0f) ? 1.0f / s : 0.0f;
}

__global__ void k_wdiff(const float* __restrict__ W2, float* __restrict__ Wd_g,
                        float* __restrict__ Wd_t) {
    int i = blockIdx.x * blockDim.x + threadIdx.x;
    if (i >= DD * DD) return;
    Wd_g[i] = W2[i] - W2[DD * DD + i];
    Wd_t[i] = W2[2 * DD * DD + i] - W2[3 * DD * DD + i];
}

__global__ void k_init(const float* __restrict__ ue, const float* __restrict__ ie,
                       __half* __restrict__ xh, float* __restrict__ acc) {
    size_t i = (size_t)blockIdx.x * blockDim.x + threadIdx.x;
    if (i >= (size_t)NN * DD) return;
    float v = (i < (size_t)NU * DD) ? ue[i] : ie[i - (size_t)NU * DD];
    xh[i] = __float2half(v);
    acc[i] = v;
}

// ---------------- map-building kernels (x-independent, run once) ----------------

__global__ void k_posU(const int* __restrict__ lst, int* __restrict__ pos, int E) {
    int p = blockIdx.x * blockDim.x + threadIdx.x;
    if (p < E) pos[lst[p]] = p;
}

__global__ void k_mapUI(const int* __restrict__ lst_i, const int* __restrict__ posU,
                        int* __restrict__ mUI, int E) {
    int p = blockIdx.x * blockDim.x + threadIdx.x;
    if (p < E) mUI[p] = posU[lst_i[p]];
}

__global__ void k_build_ui(const int* __restrict__ lst_u, const int* __restrict__ ui_u,
                           const int* __restrict__ ui_i, int* __restrict__ headU,
                           int* __restrict__ colUI, int E) {
    int p = blockIdx.x * blockDim.x + threadIdx.x;
    if (p >= E) return;
    int e = lst_u[p];
    headU[p] = ui_u[e];
    colUI[p] = ui_i[e] + NU;
}

__global__ void k_build_colI(const int* __restrict__ lst_i, const int* __restrict__ ui_u,
                             int* __restrict__ colUI, int E) {
    int p = blockIdx.x * blockDim.x + threadIdx.x;
    if (p < E) colUI[EUI + p] = ui_u[lst_i[p]];
}

__global__ void k_build_rp2(const int* __restrict__ rp_u, const int* __restrict__ rp_i,
                            const int* __restrict__ rp_uu, const int* __restrict__ rp_ii,
                            int* __restrict__ rp_ui, int* __restrict__ rp_s) {
    int t = blockIdx.x * blockDim.x + threadIdx.x;
    if (t > NN) return;
    rp_ui[t] = (t <= NU) ? rp_u[t] : rp_i[t - NU] + EUI;
    rp_s[t]  = (t <= NU) ? rp_uu[t] : rp_ii[t - NU] + EUU;
}

__global__ void k_build_gw(const int* __restrict__ rp, const int* __restrict__ col,
                           const float* __restrict__ dinv, float* __restrict__ gw, int n) {
    int r = blockIdx.x * blockDim.x + threadIdx.x;
    if (r >= n) return;
    float dh = dinv[r];
    int e1 = rp[r + 1];
    for (int p = rp[r]; p < e1; p++) gw[p] = dh * dinv[col[p]];
}

__global__ void k_build_s(const int* __restrict__ lst, const int* __restrict__ eh,
                          const int* __restrict__ et, const float* __restrict__ ew,
                          const float* __restrict__ inv, int off, int peo,
                          int* __restrict__ head, int* __restrict__ col,
                          float* __restrict__ bw, int E) {
    int p = blockIdx.x * blockDim.x + threadIdx.x;
    if (p >= E) return;
    int e = lst[p];
    int h = eh[e];
    head[peo + p] = h + off;
    col[peo + p] = et[e] + off;
    bw[peo + p] = ew[e] * inv[h];
}

// ---------------- pass A (UI, CSR order, grid-stride): c[p] fp16 ----------------

__global__ __launch_bounds__(256) void k_passA(
        const int* __restrict__ head, const int* __restrict__ col,
        const __half* __restrict__ x, const float* __restrict__ intents,
        __half* __restrict__ c_out, int E) {
    __shared__ float Wl[DD * KK];
    for (int idx = threadIdx.x; idx < DD * KK; idx += blockDim.x) Wl[idx] = intents[idx];
    __syncthreads();
    int stride = gridDim.x * blockDim.x;
    for (int p = blockIdx.x * blockDim.x + threadIdx.x; p < E; p += stride) {
        const uint4* hp = (const uint4*)(x + (size_t)head[p] * DD);
        const uint4* tp = (const uint4*)(x + (size_t)col[p] * DD);
        uint4 hraw[8], traw[8];
#pragma unroll
        for (int j = 0; j < 8; j++) hraw[j] = hp[j];
#pragma unroll
        for (int j = 0; j < 8; j++) traw[j] = tp[j];
        const __half2* h2 = (const __half2*)hraw;
        const __half2* t2 = (const __half2*)traw;
        float logit[KK];
#pragma unroll
        for (int k = 0; k < KK; k++) logit[k] = 0.f;
        float dot = 0.f;
#pragma unroll 4
        for (int l4 = 0; l4 < 16; l4++) {
            float2 ha = __half22float2(h2[2 * l4]), hb = __half22float2(h2[2 * l4 + 1]);
            float2 ta = __half22float2(t2[2 * l4]), tb = __half22float2(t2[2 * l4 + 1]);
            float p0 = ha.x * ta.x, p1 = ha.y * ta.y, p2 = hb.x * tb.x, p3 = hb.y * tb.y;
            dot += p0 + p1 + p2 + p3;
            const float* w = &Wl[l4 * 4 * KK];
#pragma unroll
            for (int k = 0; k < KK; k++)
                logit[k] += p0 * w[k] + p1 * w[KK + k] + p2 * w[2 * KK + k] + p3 * w[3 * KK + k];
        }
        float m = logit[0];
#pragma unroll
        for (int k = 1; k < KK; k++) m = fmaxf(m, logit[k]);
        float ssum = 0.f;
#pragma unroll
        for (int k = 0; k < KK; k++) { float ev = __expf(logit[k] - m); logit[k] = ev; ssum += ev; }
        float scale = 0.5f * (dot + 1.0f) / ssum;
        uint4 pk[4];
        unsigned int* u = (unsigned int*)pk;
#pragma unroll
        for (int k2 = 0; k2 < 16; k2++) {
            __half2 hh = __floats2half2_rn(logit[2 * k2] * scale, logit[2 * k2 + 1] * scale);
            u[k2] = *reinterpret_cast<const unsigned int*>(&hh);
        }
        uint4* dst = (uint4*)(c_out + (size_t)p * KK);
#pragma unroll
        for (int q = 0; q < 4; q++) dst[q] = pk[q];
    }
}

// readlane-based broadcast of packed component (l compile-time)
#define PRD(a0, a1, a2, a3, l) \
    rdlane(((l) & 3) == 0 ? (a0) : ((l) & 3) == 1 ? (a1) : ((l) & 3) == 2 ? (a2) : (a3), (l) >> 2)

// ---------------- MEGA: fused_ui (role 0/1) + passA_S-fp8 (role 2), interleaved 2:1 -----
__global__ __launch_bounds__(512) void k_mega(
        const int* __restrict__ rp, const int* __restrict__ col,
        const float* __restrict__ gw, const __half* __restrict__ cbuf,
        const int* __restrict__ mUI,
        const float* __restrict__ Wd_g, const float* __restrict__ Wd_t,
        const float* __restrict__ b2, const __half* __restrict__ x,
        __half* __restrict__ gs, __half* __restrict__ ts, float* __restrict__ zp,
        const int* __restrict__ head_s, const int* __restrict__ col_s,
        const float* __restrict__ intents, unsigned char* __restrict__ c8) {
    __shared__ float shmem[2 * DD * DD];   // 32 KB, role-dependent use
    int role = blockIdx.x % 3;
    if (role < 2) {
        // ======== fused UI: inline agg + g1 + t1 + z-preact; 64 rows/block ========
        float* Wg = shmem;
        float* Wt = shmem + DD * DD;
        for (int i = threadIdx.x; i < DD * DD; i += 512) { Wg[i] = Wd_g[i]; Wt[i] = Wd_t[i]; }
        __syncthreads();
        int fb = (blockIdx.x / 3) * 2 + role;
        int wid = threadIdx.x >> 6, lane = threadIdx.x & 63;
        int sub = lane & 15, grp = lane >> 4;
        float b2v = b2[lane];
        const uint2* xq = (const uint2*)x;
        const unsigned int* cu = (const unsigned int*)cbuf;
        int rbase = fb * ROWS_PB + wid * 8;
        for (int rr = 0; rr < 8; rr++) {
            int r = rbase + rr;
            if (r >= NN) break;
            bool item = (r >= NU);
            int e0 = rp[r], e1 = rp[r + 1];
            float a0 = 0.f, a1 = 0.f;
            for (int e = e0; e < e1; e += 4) {
                int idx = e + grp;
                if (idx < e1) {
                    int ci = item ? mUI[idx - EUI] : idx;
                    unsigned int cv = cu[(size_t)ci * 16 + sub];
                    float2 cf = __half22float2(*(const __half2*)&cv);
                    a0 += cf.x; a1 += cf.y;
                }
            }
            a0 += __shfl_xor(a0, 16, 64); a0 += __shfl_xor(a0, 32, 64);
            a1 += __shfl_xor(a1, 16, 64); a1 += __shfl_xor(a1, 32, 64);
            float2 rc;
            rc.x = (a0 != 0.f) ? 1.f / a0 : 0.f;
            rc.y = (a1 != 0.f) ? 1.f / a1 : 0.f;
            float g0 = 0, g1 = 0, g2 = 0, g3 = 0, t0 = 0, t1 = 0, t2 = 0, t3 = 0;
            float rsacc = 0.f;
            int e = e0;
            for (; e + 8 <= e1; e += 8) {
#pragma unroll
                for (int u = 0; u < 2; u++) {
                    int idx = e + 4 * u + grp;
                    int cc = col[idx];
                    float wg = gw[idx];
                    int ci = item ? mUI[idx - EUI] : idx;
                    unsigned int cv = cu[(size_t)ci * 16 + sub];
                    float2 cf = __half22float2(*(const __half2*)&cv);
                    float pd = fmaf(cf.x, rc.x, cf.y * rc.y);
                    pd += __shfl_xor(pd, 1, 64); pd += __shfl_xor(pd, 2, 64);
                    pd += __shfl_xor(pd, 4, 64); pd += __shfl_xor(pd, 8, 64);
                    float wt = pd * (1.0f / KK);
                    rsacc += wt;
                    uint2 raw = xq[(size_t)cc * 16 + sub];
                    float2 xa = __half22float2(*(const __half2*)&raw.x);
                    float2 xb = __half22float2(*(const __half2*)&raw.y);
                    g0 += wg * xa.x; g1 += wg * xa.y; g2 += wg * xb.x; g3 += wg * xb.y;
                    t0 += wt * xa.x; t1 += wt * xa.y; t2 += wt * xb.x; t3 += wt * xb.y;
                }
            }
            for (; e < e1; e += 4) {
                int idx = e + grp;
                if (idx < e1) {
                    int cc = col[idx];
                    float wg = gw[idx];
                    int ci = item ? mUI[idx - EUI] : idx;
                    unsigned int cv = cu[(size_t)ci * 16 + sub];
                    float2 cf = __half22float2(*(const __half2*)&cv);
                    float pd = fmaf(cf.x, rc.x, cf.y * rc.y);
                    pd += __shfl_xor(pd, 1, 64); pd += __shfl_xor(pd, 2, 64);
                    pd += __shfl_xor(pd, 4, 64); pd += __shfl_xor(pd, 8, 64);
                    float wt = pd * (1.0f / KK);
                    rsacc += wt;
                    uint2 raw = xq[(size_t)cc * 16 + sub];
                    float2 xa = __half22float2(*(const __half2*)&raw.x);
                    float2 xb = __half22float2(*(const __half2*)&raw.y);
                    g0 += wg * xa.x; g1 += wg * xa.y; g2 += wg * xb.x; g3 += wg * xb.y;
                    t0 += wt * xa.x; t1 += wt * xa.y; t2 += wt * xb.x; t3 += wt * xb.y;
                }
            }
#pragma unroll
            for (int off = 16; off <= 32; off <<= 1) {
                g0 += __shfl_xor(g0, off, 64); g1 += __shfl_xor(g1, off, 64);
                g2 += __shfl_xor(g2, off, 64); g3 += __shfl_xor(g3, off, 64);
                t0 += __shfl_xor(t0, off, 64); t1 += __shfl_xor(t1, off, 64);
                t2 += __shfl_xor(t2, off, 64); t3 += __shfl_xor(t3, off, 64);
                rsacc += __shfl_xor(rsacc, off, 64);
            }
            float rsv = (rsacc != 0.f) ? 1.0f / rsacc : 0.f;
            t0 *= rsv; t1 *= rsv; t2 *= rsv; t3 *= rsv;
            float ss = t0 * t0 + t1 * t1 + t2 * t2 + t3 * t3;
            ss += __shfl_xor(ss, 1, 64); ss += __shfl_xor(ss, 2, 64);
            ss += __shfl_xor(ss, 4, 64); ss += __shfl_xor(ss, 8, 64);
            float inv_n = 1.0f / fmaxf(sqrtf(ss), 1e-12f);
            t0 *= inv_n; t1 *= inv_n; t2 *= inv_n; t3 *= inv_n;
            float zv = b2v;
#pragma unroll
            for (int l = 0; l < DD; l++) {
                float gl = PRD(g0, g1, g2, g3, l);
                float tl = PRD(t0, t1, t2, t3, l);
                zv += gl * Wg[l * DD + lane] + tl * Wt[l * DD + lane];
            }
            float ga0 = __shfl(g0, lane >> 2, 64), ga1 = __shfl(g1, lane >> 2, 64);
            float ga2 = __shfl(g2, lane >> 2, 64), ga3 = __shfl(g3, lane >> 2, 64);
            float ta0 = __shfl(t0, lane >> 2, 64), ta1 = __shfl(t1, lane >> 2, 64);
            float ta2 = __shfl(t2, lane >> 2, 64), ta3 = __shfl(t3, lane >> 2, 64);
            int j = lane & 3;
            float gsv = j == 0 ? ga0 : j == 1 ? ga1 : j == 2 ? ga2 : ga3;
            float tsv = j == 0 ? ta0 : j == 1 ? ta1 : j == 2 ? ta2 : ta3;
            size_t oi = (size_t)r * DD + lane;
            gs[oi] = __float2half(gsv);
            ts[oi] = __float2half(tsv);
            zp[oi] = zv;
        }
    } else {
        // ======== passA for S graph, fp8 output ========
        float* Wl = shmem;
        for (int idx = threadIdx.x; idx < DD * KK; idx += 512) Wl[idx] = intents[idx];
        __syncthreads();
        int pb = blockIdx.x / 3;
        const int ES = EUU + EII;
        int stride = PB * 512;
        for (int p = pb * 512 + threadIdx.x; p < ES; p += stride) {
            const uint4* hp = (const uint4*)(x + (size_t)head_s[p] * DD);
            const uint4* tp = (const uint4*)(x + (size_t)col_s[p] * DD);
            uint4 hraw[8], traw[8];
#pragma unroll
            for (int j = 0; j < 8; j++) hraw[j] = hp[j];
#pragma unroll
            for (int j = 0; j < 8; j++) traw[j] = tp[j];
            const __half2* h2 = (const __half2*)hraw;
            const __half2* t2 = (const __half2*)traw;
            float logit[KK];
#pragma unroll
            for (int k = 0; k < KK; k++) logit[k] = 0.f;
            float dot = 0.f;
#pragma unroll 4
            for (int l4 = 0; l4 < 16; l4++) {
                float2 ha = __half22float2(h2[2 * l4]), hb = __half22float2(h2[2 * l4 + 1]);
                float2 ta = __half22float2(t2[2 * l4]), tb = __half22float2(t2[2 * l4 + 1]);
                float p0 = ha.x * ta.x, p1 = ha.y * ta.y, p2 = hb.x * tb.x, p3 = hb.y * tb.y;
                dot += p0 + p1 + p2 + p3;
                const float* w = &Wl[l4 * 4 * KK];
#pragma unroll
                for (int k = 0; k < KK; k++)
                    logit[k] += p0 * w[k] + p1 * w[KK + k] + p2 * w[2 * KK + k] + p3 * w[3 * KK + k];
            }
            float m = logit[0];
#pragma unroll
            for (int k = 1; k < KK; k++) m = fmaxf(m, logit[k]);
            float ssum = 0.f;
#pragma unroll
            for (int k = 0; k < KK; k++) { float ev = __expf(logit[k] - m); logit[k] = ev; ssum += ev; }
            float scale = 0.5f * (dot + 1.0f) / ssum;
            unsigned int w8[8];
#pragma unroll
            for (int q = 0; q < 8; q++) {
                w8[q] = enc8(logit[4 * q] * scale)
                      | (enc8(logit[4 * q + 1] * scale) << 8)
                      | (enc8(logit[4 * q + 2] * scale) << 16)
                      | (enc8(logit[4 * q + 3] * scale) << 24);
            }
            uint4* dst = (uint4*)(c8 + (size_t)p * 32);
            dst[0] = make_uint4(w8[0], w8[1], w8[2], w8[3]);
            dst[1] = make_uint4(w8[4], w8[5], w8[6], w8[7]);
        }
    }
}

// ---------------- fused finalize: inline agg + g2 + t2 + gate + combine (fp8 c) ---------
__global__ __launch_bounds__(512) void k_fused_fin(
        const int* __restrict__ rp, const int* __restrict__ col,
        const float* __restrict__ bw, const unsigned char* __restrict__ c8,
        const float* __restrict__ W1, const float* __restrict__ W3,
        const __half* __restrict__ x, const __half* __restrict__ gs,
        const __half* __restrict__ ts, const float* __restrict__ zp,
        __half* __restrict__ xh_out, float* __restrict__ acc, int nrows) {
    __shared__ float Wa[DD * DD];
    __shared__ float Wb[DD * DD];
    for (int i = threadIdx.x; i < DD * DD; i += 512) { Wa[i] = W1[i]; Wb[i] = W3[i]; }
    __syncthreads();
    int wid = threadIdx.x >> 6, lane = threadIdx.x & 63;
    int sub = lane & 15, grp = lane >> 4;
    const uint2* xq = (const uint2*)x;
    const unsigned short* cs = (const unsigned short*)c8;
    int rbase = blockIdx.x * ROWS_PB + wid * 8;
    for (int rr = 0; rr < 8; rr++) {
        int r = rbase + rr;
        if (r >= nrows) break;
        int e0 = rp[r], e1 = rp[r + 1];
        float a0 = 0.f, a1 = 0.f;
        for (int e = e0; e < e1; e += 4) {
            int idx = e + grp;
            if (idx < e1) {
                unsigned int cv = cs[(size_t)idx * 16 + sub];
                a0 += dec8(cv & 0xff); a1 += dec8(cv >> 8);
            }
        }
        a0 += __shfl_xor(a0, 16, 64); a0 += __shfl_xor(a0, 32, 64);
        a1 += __shfl_xor(a1, 16, 64); a1 += __shfl_xor(a1, 32, 64);
        float2 rc;
        rc.x = (a0 != 0.f) ? 1.f / a0 : 0.f;
        rc.y = (a1 != 0.f) ? 1.f / a1 : 0.f;
        float g0 = 0, g1 = 0, g2 = 0, g3 = 0, t0 = 0, t1 = 0, t2 = 0, t3 = 0;
        float rsacc = 0.f;
        int e = e0;
        for (; e + 8 <= e1; e += 8) {
#pragma unroll
            for (int u = 0; u < 2; u++) {
                int idx = e + 4 * u + grp;
                int cc = col[idx];
                float wg = bw[idx];
                unsigned int cv = cs[(size_t)idx * 16 + sub];
                float cx = dec8(cv & 0xff), cy = dec8(cv >> 8);
                float pd = fmaf(cx, rc.x, cy * rc.y);
                pd += __shfl_xor(pd, 1, 64); pd += __shfl_xor(pd, 2, 64);
                pd += __shfl_xor(pd, 4, 64); pd += __shfl_xor(pd, 8, 64);
                float wt = pd * (1.0f / KK);
                rsacc += wt;
                uint2 raw = xq[(size_t)cc * 16 + sub];
                float2 xa = __half22float2(*(const __half2*)&raw.x);
                float2 xb = __half22float2(*(const __half2*)&raw.y);
                g0 += wg * xa.x; g1 += wg * xa.y; g2 += wg * xb.x; g3 += wg * xb.y;
                t0 += wt * xa.x; t1 += wt * xa.y; t2 += wt * xb.x; t3 += wt * xb.y;
            }
        }
        for (; e < e1; e += 4) {
            int idx = e + grp;
            if (idx < e1) {
                int cc = col[idx];
                float wg = bw[idx];
                unsigned int cv = cs[(size_t)idx * 16 + sub];
                float cx = dec8(cv & 0xff), cy = dec8(cv >> 8);
                float pd = fmaf(cx, rc.x, cy * rc.y);
                pd += __shfl_xor(pd, 1, 64); pd += __shfl_xor(pd, 2, 64);
                pd += __shfl_xor(pd, 4, 64); pd += __shfl_xor(pd, 8, 64);
                float wt = pd * (1.0f / KK);
                rsacc += wt;
                uint2 raw = xq[(size_t)cc * 16 + sub];
                float2 xa = __half22float2(*(const __half2*)&raw.x);
                float2 xb = __half22float2(*(const __half2*)&raw.y);
                g0 += wg * xa.x; g1 += wg * xa.y; g2 += wg * xb.x; g3 += wg * xb.y;
                t0 += wt * xa.x; t1 += wt * xa.y; t2 += wt * xb.x; t3 += wt * xb.y;
            }
        }
#pragma unroll
        for (int off = 16; off <= 32; off <<= 1) {
            g0 += __shfl_xor(g0, off, 64); g1 += __shfl_xor(g1, off, 64);
            g2 += __shfl_xor(g2, off, 64); g3 += __shfl_xor(g3, off, 64);
            t0 += __shfl_xor(t0, off, 64); t1 += __shfl_xor(t1, off, 64);
            t2 += __shfl_xor(t2, off, 64); t3 += __shfl_xor(t3, off, 64);
            rsacc += __shfl_xor(rsacc, off, 64);
        }
        float rsv = (rsacc != 0.f) ? 1.0f / rsacc : 0.f;
        t0 *= rsv; t1 *= rsv; t2 *= rsv; t3 *= rsv;
        float ss = t0 * t0 + t1 * t1 + t2 * t2 + t3 * t3;
        ss += __shfl_xor(ss, 1, 64); ss += __shfl_xor(ss, 2, 64);
        ss += __shfl_xor(ss, 4, 64); ss += __shfl_xor(ss, 8, 64);
        float inv_n = 1.0f / fmaxf(sqrtf(ss), 1e-12f);
        t0 *= inv_n; t1 *= inv_n; t2 *= inv_n; t3 *= inv_n;
        uint2 gp2 = ((const uint2*)(gs + (size_t)r * DD))[sub];
        uint2 tp2 = ((const uint2*)(ts + (size_t)r * DD))[sub];
        float2 gpa = __half22float2(*(const __half2*)&gp2.x);
        float2 gpb = __half22float2(*(const __half2*)&gp2.y);
        float2 tpa = __half22float2(*(const __half2*)&tp2.x);
        float2 tpb = __half22float2(*(const __half2*)&tp2.y);
        float gf0 = gpa.x + g0, gf1 = gpa.y + g1, gf2 = gpb.x + g2, gf3 = gpb.y + g3;
        float tf0 = tpa.x + t0, tf1 = tpa.y + t1, tf2 = tpb.x + t2, tf3 = tpb.y + t3;
        size_t oi = (size_t)r * DD + lane;
        float zv = zp[oi];
#pragma unroll
        for (int l = 0; l < DD; l++) {
            float gl = PRD(gf0, gf1, gf2, gf3, l);
            float tl = PRD(tf0, tf1, tf2, tf3, l);
            zv += gl * Wa[l * DD + lane] + tl * Wb[l * DD + lane];
        }
        float ga0 = __shfl(gf0, lane >> 2, 64), ga1 = __shfl(gf1, lane >> 2, 64);
        float ga2 = __shfl(gf2, lane >> 2, 64), ga3 = __shfl(gf3, lane >> 2, 64);
        float ta0 = __shfl(tf0, lane >> 2, 64), ta1 = __shfl(tf1, lane >> 2, 64);
        float ta2 = __shfl(tf2, lane >> 2, 64), ta3 = __shfl(tf3, lane >> 2, 64);
        int j = lane & 3;
        float gfin = j == 0 ? ga0 : j == 1 ? ga1 : j == 2 ? ga2 : ga3;
        float tfin = j == 0 ? ta0 : j == 1 ? ta1 : j == 2 ? ta2 : ta3;
        float gate = 1.0f / (1.0f + __expf(-zv));
        float xn = gate * gfin + (1.0f - gate) * tfin;
        xh_out[oi] = __float2half(xn);
        acc[oi] += xn;
    }
}

// ---------------- host launcher ----------------

extern "C" void kernel_launch(void* const* d_in, const int* in_sizes, int n_in,
                              void* d_out, int out_size, void* d_ws, size_t ws_size,
                              hipStream_t stream) {
    const float* user_emb = (const float*)d_in[0];
    const float* item_emb = (const float*)d_in[1];
    const float* intents  = (const float*)d_in[2];
    const float* W2       = (const float*)d_in[3];
    const float* b2       = (const float*)d_in[4];
    const float* uu_w     = (const float*)d_in[5];
    const float* ii_w     = (const float*)d_in[6];
    const int*   ui_u     = (const int*)d_in[7];
    const int*   ui_i     = (const int*)d_in[8];
    const int*   uu_h     = (const int*)d_in[9];
    const int*   uu_t     = (const int*)d_in[10];
    const int*   ii_h     = (const int*)d_in[11];
    const int*   ii_t     = (const int*)d_in[12];
    float* acc = (float*)d_out;

    char* pw = (char*)d_ws;
    auto allocb = [&](size_t nbytes) -> char* {
        char* r = pw;
        pw += (nbytes + 255) & ~(size_t)255;
        return r;
    };
    // ~252 MB total (safe: 256+ proven in rounds 9/10)
    __half* gs   = (__half*)allocb((size_t)NN * DD * 2);
    __half* ts   = (__half*)allocb((size_t)NN * DD * 2);
    float* zp    = (float*)allocb((size_t)NN * DD * 4);
    __half* xh0  = (__half*)allocb((size_t)NN * DD * 2);
    __half* xh1  = (__half*)allocb((size_t)NN * DD * 2);
    __half* c    = (__half*)allocb((size_t)EUI * KK * 2);        // 64 MB (UI); build scratch aliases
    unsigned char* c8 = (unsigned char*)allocb((size_t)(EUU + EII) * KK); // 32 MB (S, fp8)
    float* dinv  = (float*)allocb((size_t)NN * 4);
    float* iuu   = (float*)allocb((size_t)NU * 4);
    float* iii   = (float*)allocb((size_t)NI * 4);
    float* Wd_g  = (float*)allocb((size_t)DD * DD * 4);
    float* Wd_t  = (float*)allocb((size_t)DD * DD * 4);
    int* rp_u    = (int*)allocb(((size_t)NU + 1) * 4);
    int* rp_i    = (int*)allocb(((size_t)NI + 1) * 4);
    int* rp_uu   = (int*)allocb(((size_t)NU + 1) * 4);
    int* rp_ii   = (int*)allocb(((size_t)NI + 1) * 4);
    int* rp_ui   = (int*)allocb(((size_t)NN + 1) * 4);
    int* rp_s    = (int*)allocb(((size_t)NN + 1) * 4);
    int* headU   = (int*)allocb((size_t)EUI * 4);
    int* colUI   = (int*)allocb((size_t)2 * EUI * 4);
    int* head_s  = (int*)allocb((size_t)(EUU + EII) * 4);
    int* col_s   = (int*)allocb((size_t)(EUU + EII) * 4);
    float* bw_s  = (float*)allocb((size_t)(EUU + EII) * 4);
    int* mUI     = (int*)allocb((size_t)EUI * 4);
    float* gwUI  = (float*)allocb((size_t)2 * EUI * 4);

    char* ca = (char*)c;
    int* cur    = (int*)ca;  ca += ((size_t)NU * 4 + 255) & ~(size_t)255;
    int* lst_u  = (int*)ca;  ca += ((size_t)EUI * 4 + 255) & ~(size_t)255;
    int* lst_i  = (int*)ca;  ca += ((size_t)EUI * 4 + 255) & ~(size_t)255;
    int* lst_uu = (int*)ca;  ca += ((size_t)EUU * 4 + 255) & ~(size_t)255;
    int* lst_ii = (int*)ca;  ca += ((size_t)EII * 4 + 255) & ~(size_t)255;
    int* posU   = (int*)ca;

    const int B = 256;

    auto build_csr = [&](const int* h, int E, int n, int* rp, int* lst) {
        hipMemsetAsync(cur, 0, (size_t)n * 4, stream);
        k_count<<<cdiv(E, B), B, 0, stream>>>(h, cur, E);
        k_scan<<<1, 1024, 0, stream>>>(cur, rp, n);
        hipMemsetAsync(cur, 0, (size_t)n * 4, stream);
        k_scatter<<<cdiv(E, B), B, 0, stream>>>(h, rp, cur, lst, E);
    };

    build_csr(ui_u, EUI, NU, rp_u, lst_u);
    build_csr(ui_i, EUI, NI, rp_i, lst_i);
    build_csr(uu_h, EUU, NU, rp_uu, lst_uu);
    build_csr(ii_h, EII, NI, rp_ii, lst_ii);
    k_dinv<<<cdiv(NN, B), B, 0, stream>>>(rp_u, rp_i, dinv);
    k_rowsum_inv<<<cdiv(NU, B), B, 0, stream>>>(rp_uu, lst_uu, uu_w, iuu, NU);
    k_rowsum_inv<<<cdiv(NI, B), B, 0, stream>>>(rp_ii, lst_ii, ii_w, iii, NI);
    k_build_rp2<<<cdiv(NN + 1, B), B, 0, stream>>>(rp_u, rp_i, rp_uu, rp_ii, rp_ui, rp_s);
    k_build_ui<<<cdiv(EUI, B), B, 0, stream>>>(lst_u, ui_u, ui_i, headU, colUI, EUI);
    k_build_colI<<<cdiv(EUI, B), B, 0, stream>>>(lst_i, ui_u, colUI, EUI);
    k_posU<<<cdiv(EUI, B), B, 0, stream>>>(lst_u, posU, EUI);
    k_mapUI<<<cdiv(EUI, B), B, 0, stream>>>(lst_i, posU, mUI, EUI);
    k_build_s<<<cdiv(EUU, B), B, 0, stream>>>(lst_uu, uu_h, uu_t, uu_w, iuu, 0, 0,
                                              head_s, col_s, bw_s, EUU);
    k_build_s<<<cdiv(EII, B), B, 0, stream>>>(lst_ii, ii_h, ii_t, ii_w, iii, NU, EUU,
                                              head_s, col_s, bw_s, EII);
    k_build_gw<<<cdiv(NN, B), B, 0, stream>>>(rp_ui, colUI, dinv, gwUI, NN);
    k_wdiff<<<cdiv(DD * DD, B), B, 0, stream>>>(W2, Wd_g, Wd_t);
    k_init<<<cdiv((long)NN * DD, B), B, 0, stream>>>(user_emb, item_emb, xh0, acc);

    for (int layer = 0; layer < 2; ++layer) {
        const __half* xin = (layer == 0) ? xh0 : xh1;
        __half* xout = (layer == 0) ? xh1 : xh0;

        // 1) passA for UI (fp16 c)
        k_passA<<<1024, B, 0, stream>>>(headU, colUI, xin, intents, c, EUI);
        // 2) MEGA: fused_ui ∥ passA_S(fp8 c8), interleaved 2:1
        k_mega<<<MEGA_GRID, 512, 0, stream>>>(rp_ui, colUI, gwUI, c, mUI,
                                              Wd_g, Wd_t, b2, xin, gs, ts, zp,
                                              head_s, col_s, intents, c8);
        // 3) fused finalize (reads fp8 c8)
        k_fused_fin<<<FB, 512, 0, stream>>>(rp_s, col_s, bw_s, c8,
                                            W2 + DD * DD, W2 + 3 * DD * DD,
                                            xin, gs, ts, zp, xout, acc, NN);
    }
}

// Round 15
// 2196.523 us; speedup vs baseline: 1.0576x; 1.0446x over previous
//
#include <hip/hip_runtime.h>
#include <hip/hip_fp16.h>

#define NU 100000
#define NI 50000
#define NN 150000
#define DD 64
#define KK 32
#define EUI 1000000
#define EUU 500000
#define EII 500000
#define ROWS_PB 64

static inline int cdiv(long a, int b) { return (int)((a + b - 1) / b); }

__device__ __forceinline__ float rdlane(float v, int l) {
    return __int_as_float(__builtin_amdgcn_readlane(__float_as_int(v), l));
}

// ---------------- CSR build ----------------

__global__ void k_count(const int* __restrict__ h, int* __restrict__ cnt, int E) {
    int e = blockIdx.x * blockDim.x + threadIdx.x;
    if (e < E) atomicAdd(&cnt[h[e]], 1);
}

__global__ __launch_bounds__(1024) void k_scan(const int* __restrict__ cnt,
                                               int* __restrict__ rp, int n) {
    __shared__ int wsum[16];
    __shared__ int carry_s;
    int tid = threadIdx.x;
    int lane = tid & 63, wid = tid >> 6;
    if (tid == 0) carry_s = 0;
    __syncthreads();
    for (int base = 0; base < n; base += 1024) {
        int i = base + tid;
        int v = (i < n) ? cnt[i] : 0;
        int s = v;
#pragma unroll
        for (int off = 1; off < 64; off <<= 1) {
            int t = __shfl_up(s, off, 64);
            if (lane >= off) s += t;
        }
        if (lane == 63) wsum[wid] = s;
        __syncthreads();
        int woff = 0, total = 0;
#pragma unroll
        for (int w = 0; w < 16; w++) { int ws = wsum[w]; total += ws; if (w < wid) woff += ws; }
        int carry = carry_s;
        if (i < n) rp[i] = carry + woff + (s - v);
        __syncthreads();
        if (tid == 0) carry_s = carry + total;
        __syncthreads();
    }
    if (tid == 0) rp[n] = carry_s;
}

__global__ void k_scatter(const int* __restrict__ h, const int* __restrict__ rp,
                          int* __restrict__ cur, int* __restrict__ lst, int E) {
    int e = blockIdx.x * blockDim.x + threadIdx.x;
    if (e >= E) return;
    int r = h[e];
    int p = rp[r] + atomicAdd(&cur[r], 1);
    lst[p] = e;
}

__global__ void k_dinv(const int* __restrict__ rpu, const int* __restrict__ rpi,
                       float* __restrict__ dinv) {
    int t = blockIdx.x * blockDim.x + threadIdx.x;
    if (t >= NN) return;
    int deg = (t < NU) ? rpu[t + 1] - rpu[t] : rpi[t - NU + 1] - rpi[t - NU];
    dinv[t] = deg > 0 ? rsqrtf((float)deg) : 0.0f;
}

__global__ void k_rowsum_inv(const int* __restrict__ rp, const int* __restrict__ lst,
                             const float* __restrict__ w, float* __restrict__ out, int n) {
    int r = blockIdx.x * blockDim.x + threadIdx.x;
    if (r >= n) return;
    float s = 0.f;
    int e1 = rp[r + 1];
    for (int e = rp[r]; e < e1; e++) s += w[lst[e]];
    out[r] = (s != 0.0f) ? 1.0f / s : 0.0f;
}

__global__ void k_wdiff(const float* __restrict__ W2, float* __restrict__ Wd_g,
                        float* __restrict__ Wd_t) {
    int i = blockIdx.x * blockDim.x + threadIdx.x;
    if (i >= DD * DD) return;
    Wd_g[i] = W2[i] - W2[DD * DD + i];
    Wd_t[i] = W2[2 * DD * DD + i] - W2[3 * DD * DD + i];
}

__global__ void k_init(const float* __restrict__ ue, const float* __restrict__ ie,
                       __half* __restrict__ xh, float* __restrict__ acc) {
    size_t i = (size_t)blockIdx.x * blockDim.x + threadIdx.x;
    if (i >= (size_t)NN * DD) return;
    float v = (i < (size_t)NU * DD) ? ue[i] : ie[i - (size_t)NU * DD];
    xh[i] = __float2half(v);
    acc[i] = v;
}

// ---------------- map-building kernels (x-independent, run once) ----------------

__global__ void k_posU(const int* __restrict__ lst, int* __restrict__ pos, int E) {
    int p = blockIdx.x * blockDim.x + threadIdx.x;
    if (p < E) pos[lst[p]] = p;
}

__global__ void k_mapUI(const int* __restrict__ lst_i, const int* __restrict__ posU,
                        int* __restrict__ mUI, int E) {
    int p = blockIdx.x * blockDim.x + threadIdx.x;
    if (p < E) mUI[p] = posU[lst_i[p]];
}

__global__ void k_build_ui(const int* __restrict__ lst_u, const int* __restrict__ ui_u,
                           const int* __restrict__ ui_i, int* __restrict__ headU,
                           int* __restrict__ colUI, int E) {
    int p = blockIdx.x * blockDim.x + threadIdx.x;
    if (p >= E) return;
    int e = lst_u[p];
    headU[p] = ui_u[e];
    colUI[p] = ui_i[e] + NU;
}

__global__ void k_build_colI(const int* __restrict__ lst_i, const int* __restrict__ ui_u,
                             int* __restrict__ colUI, int E) {
    int p = blockIdx.x * blockDim.x + threadIdx.x;
    if (p < E) colUI[EUI + p] = ui_u[lst_i[p]];
}

__global__ void k_build_rp2(const int* __restrict__ rp_u, const int* __restrict__ rp_i,
                            const int* __restrict__ rp_uu, const int* __restrict__ rp_ii,
                            int* __restrict__ rp_ui, int* __restrict__ rp_s) {
    int t = blockIdx.x * blockDim.x + threadIdx.x;
    if (t > NN) return;
    rp_ui[t] = (t <= NU) ? rp_u[t] : rp_i[t - NU] + EUI;
    rp_s[t]  = (t <= NU) ? rp_uu[t] : rp_ii[t - NU] + EUU;
}

__global__ void k_build_gw(const int* __restrict__ rp, const int* __restrict__ col,
                           const float* __restrict__ dinv, float* __restrict__ gw, int n) {
    int r = blockIdx.x * blockDim.x + threadIdx.x;
    if (r >= n) return;
    float dh = dinv[r];
    int e1 = rp[r + 1];
    for (int p = rp[r]; p < e1; p++) gw[p] = dh * dinv[col[p]];
}

__global__ void k_build_s(const int* __restrict__ lst, const int* __restrict__ eh,
                          const int* __restrict__ et, const float* __restrict__ ew,
                          const float* __restrict__ inv, int off, int peo,
                          int* __restrict__ head, int* __restrict__ col,
                          float* __restrict__ bw, int E) {
    int p = blockIdx.x * blockDim.x + threadIdx.x;
    if (p >= E) return;
    int e = lst[p];
    int h = eh[e];
    head[peo + p] = h + off;
    col[peo + p] = et[e] + off;
    bw[peo + p] = ew[e] * inv[h];
}

// ---------------- pass A (CSR order, grid-stride): c[p] = alpha * dist, fp16 -----------

__global__ __launch_bounds__(256) void k_passA(
        const int* __restrict__ head, const int* __restrict__ col,
        const __half* __restrict__ x, const float* __restrict__ intents,
        __half* __restrict__ c_out, int E) {
    __shared__ float Wl[DD * KK];
    for (int idx = threadIdx.x; idx < DD * KK; idx += blockDim.x) Wl[idx] = intents[idx];
    __syncthreads();
    int stride = gridDim.x * blockDim.x;
    for (int p = blockIdx.x * blockDim.x + threadIdx.x; p < E; p += stride) {
        const uint4* hp = (const uint4*)(x + (size_t)head[p] * DD);
        const uint4* tp = (const uint4*)(x + (size_t)col[p] * DD);
        uint4 hraw[8], traw[8];
#pragma unroll
        for (int j = 0; j < 8; j++) hraw[j] = hp[j];
#pragma unroll
        for (int j = 0; j < 8; j++) traw[j] = tp[j];
        const __half2* h2 = (const __half2*)hraw;
        const __half2* t2 = (const __half2*)traw;
        float logit[KK];
#pragma unroll
        for (int k = 0; k < KK; k++) logit[k] = 0.f;
        float dot = 0.f;
#pragma unroll 4
        for (int l4 = 0; l4 < 16; l4++) {
            float2 ha = __half22float2(h2[2 * l4]), hb = __half22float2(h2[2 * l4 + 1]);
            float2 ta = __half22float2(t2[2 * l4]), tb = __half22float2(t2[2 * l4 + 1]);
            float p0 = ha.x * ta.x, p1 = ha.y * ta.y, p2 = hb.x * tb.x, p3 = hb.y * tb.y;
            dot += p0 + p1 + p2 + p3;
            const float* w = &Wl[l4 * 4 * KK];
#pragma unroll
            for (int k = 0; k < KK; k++)
                logit[k] += p0 * w[k] + p1 * w[KK + k] + p2 * w[2 * KK + k] + p3 * w[3 * KK + k];
        }
        float m = logit[0];
#pragma unroll
        for (int k = 1; k < KK; k++) m = fmaxf(m, logit[k]);
        float ssum = 0.f;
#pragma unroll
        for (int k = 0; k < KK; k++) { float ev = __expf(logit[k] - m); logit[k] = ev; ssum += ev; }
        float scale = 0.5f * (dot + 1.0f) / ssum;
        uint4 pk[4];
        unsigned int* u = (unsigned int*)pk;
#pragma unroll
        for (int k2 = 0; k2 < 16; k2++) {
            __half2 hh = __floats2half2_rn(logit[2 * k2] * scale, logit[2 * k2 + 1] * scale);
            u[k2] = *reinterpret_cast<const unsigned int*>(&hh);
        }
        uint4* dst = (uint4*)(c_out + (size_t)p * KK);
#pragma unroll
        for (int q = 0; q < 4; q++) dst[q] = pk[q];
    }
}

// readlane-based broadcast of packed component (l compile-time)
#define PRD(a0, a1, a2, a3, l) \
    rdlane(((l) & 3) == 0 ? (a0) : ((l) & 3) == 1 ? (a1) : ((l) & 3) == 2 ? (a2) : (a3), (l) >> 2)

// ---------------- fused UI: inline agg + g1 + t1 + z-preact; 64 rows/block --------------
__global__ __launch_bounds__(512) void k_fused_ui(
        const int* __restrict__ rp, const int* __restrict__ col,
        const float* __restrict__ gw, const __half* __restrict__ cbuf,
        const int* __restrict__ mUI,
        const float* __restrict__ Wd_g, const float* __restrict__ Wd_t,
        const float* __restrict__ b2, const __half* __restrict__ x,
        __half* __restrict__ gs, __half* __restrict__ ts,
        float* __restrict__ zp, int nrows) {
    __shared__ float Wg[DD * DD];
    __shared__ float Wt[DD * DD];
    for (int i = threadIdx.x; i < DD * DD; i += 512) { Wg[i] = Wd_g[i]; Wt[i] = Wd_t[i]; }
    __syncthreads();
    int wid = threadIdx.x >> 6, lane = threadIdx.x & 63;
    int sub = lane & 15, grp = lane >> 4;
    float b2v = b2[lane];
    const uint2* xq = (const uint2*)x;
    const unsigned int* cu = (const unsigned int*)cbuf;
    int rbase = blockIdx.x * ROWS_PB + wid * 8;
    for (int rr = 0; rr < 8; rr++) {
        int r = rbase + rr;
        if (r >= nrows) break;
        bool item = (r >= NU);
        int e0 = rp[r], e1 = rp[r + 1];
        float a0 = 0.f, a1 = 0.f;
        for (int e = e0; e < e1; e += 4) {
            int idx = e + grp;
            if (idx < e1) {
                int ci = item ? mUI[idx - EUI] : idx;
                unsigned int cv = cu[(size_t)ci * 16 + sub];
                float2 cf = __half22float2(*(const __half2*)&cv);
                a0 += cf.x; a1 += cf.y;
            }
        }
        a0 += __shfl_xor(a0, 16, 64); a0 += __shfl_xor(a0, 32, 64);
        a1 += __shfl_xor(a1, 16, 64); a1 += __shfl_xor(a1, 32, 64);
        float2 rc;
        rc.x = (a0 != 0.f) ? 1.f / a0 : 0.f;
        rc.y = (a1 != 0.f) ? 1.f / a1 : 0.f;
        float g0 = 0, g1 = 0, g2 = 0, g3 = 0, t0 = 0, t1 = 0, t2 = 0, t3 = 0;
        float rsacc = 0.f;
        int e = e0;
        for (; e + 8 <= e1; e += 8) {
#pragma unroll
            for (int u = 0; u < 2; u++) {
                int idx = e + 4 * u + grp;
                int cc = col[idx];
                float wg = gw[idx];
                int ci = item ? mUI[idx - EUI] : idx;
                unsigned int cv = cu[(size_t)ci * 16 + sub];
                float2 cf = __half22float2(*(const __half2*)&cv);
                float pd = fmaf(cf.x, rc.x, cf.y * rc.y);
                pd += __shfl_xor(pd, 1, 64); pd += __shfl_xor(pd, 2, 64);
                pd += __shfl_xor(pd, 4, 64); pd += __shfl_xor(pd, 8, 64);
                float wt = pd * (1.0f / KK);
                rsacc += wt;
                uint2 raw = xq[(size_t)cc * 16 + sub];
                float2 xa = __half22float2(*(const __half2*)&raw.x);
                float2 xb = __half22float2(*(const __half2*)&raw.y);
                g0 += wg * xa.x; g1 += wg * xa.y; g2 += wg * xb.x; g3 += wg * xb.y;
                t0 += wt * xa.x; t1 += wt * xa.y; t2 += wt * xb.x; t3 += wt * xb.y;
            }
        }
        for (; e < e1; e += 4) {
            int idx = e + grp;
            if (idx < e1) {
                int cc = col[idx];
                float wg = gw[idx];
                int ci = item ? mUI[idx - EUI] : idx;
                unsigned int cv = cu[(size_t)ci * 16 + sub];
                float2 cf = __half22float2(*(const __half2*)&cv);
                float pd = fmaf(cf.x, rc.x, cf.y * rc.y);
                pd += __shfl_xor(pd, 1, 64); pd += __shfl_xor(pd, 2, 64);
                pd += __shfl_xor(pd, 4, 64); pd += __shfl_xor(pd, 8, 64);
                float wt = pd * (1.0f / KK);
                rsacc += wt;
                uint2 raw = xq[(size_t)cc * 16 + sub];
                float2 xa = __half22float2(*(const __half2*)&raw.x);
                float2 xb = __half22float2(*(const __half2*)&raw.y);
                g0 += wg * xa.x; g1 += wg * xa.y; g2 += wg * xb.x; g3 += wg * xb.y;
                t0 += wt * xa.x; t1 += wt * xa.y; t2 += wt * xb.x; t3 += wt * xb.y;
            }
        }
#pragma unroll
        for (int off = 16; off <= 32; off <<= 1) {
            g0 += __shfl_xor(g0, off, 64); g1 += __shfl_xor(g1, off, 64);
            g2 += __shfl_xor(g2, off, 64); g3 += __shfl_xor(g3, off, 64);
            t0 += __shfl_xor(t0, off, 64); t1 += __shfl_xor(t1, off, 64);
            t2 += __shfl_xor(t2, off, 64); t3 += __shfl_xor(t3, off, 64);
            rsacc += __shfl_xor(rsacc, off, 64);
        }
        float rsv = (rsacc != 0.f) ? 1.0f / rsacc : 0.f;
        t0 *= rsv; t1 *= rsv; t2 *= rsv; t3 *= rsv;
        float ss = t0 * t0 + t1 * t1 + t2 * t2 + t3 * t3;
        ss += __shfl_xor(ss, 1, 64); ss += __shfl_xor(ss, 2, 64);
        ss += __shfl_xor(ss, 4, 64); ss += __shfl_xor(ss, 8, 64);
        float inv_n = 1.0f / fmaxf(sqrtf(ss), 1e-12f);
        t0 *= inv_n; t1 *= inv_n; t2 *= inv_n; t3 *= inv_n;
        float zv = b2v;
#pragma unroll
        for (int l = 0; l < DD; l++) {
            float gl = PRD(g0, g1, g2, g3, l);
            float tl = PRD(t0, t1, t2, t3, l);
            zv += gl * Wg[l * DD + lane] + tl * Wt[l * DD + lane];
        }
        float ga0 = __shfl(g0, lane >> 2, 64), ga1 = __shfl(g1, lane >> 2, 64);
        float ga2 = __shfl(g2, lane >> 2, 64), ga3 = __shfl(g3, lane >> 2, 64);
        float ta0 = __shfl(t0, lane >> 2, 64), ta1 = __shfl(t1, lane >> 2, 64);
        float ta2 = __shfl(t2, lane >> 2, 64), ta3 = __shfl(t3, lane >> 2, 64);
        int j = lane & 3;
        float gsv = j == 0 ? ga0 : j == 1 ? ga1 : j == 2 ? ga2 : ga3;
        float tsv = j == 0 ? ta0 : j == 1 ? ta1 : j == 2 ? ta2 : ta3;
        size_t oi = (size_t)r * DD + lane;
        gs[oi] = __float2half(gsv);
        ts[oi] = __float2half(tsv);
        zp[oi] = zv;
    }
}

// ---------------- fused finalize: inline agg + g2 + t2 + gate + combine -----------------
__global__ __launch_bounds__(512) void k_fused_fin(
        const int* __restrict__ rp, const int* __restrict__ col,
        const float* __restrict__ bw, const __half* __restrict__ cbuf,
        const float* __restrict__ W1, const float* __restrict__ W3,
        const __half* __restrict__ x, const __half* __restrict__ gs,
        const __half* __restrict__ ts, const float* __restrict__ zp,
        __half* __restrict__ xh_out, float* __restrict__ acc, int nrows) {
    __shared__ float Wa[DD * DD];
    __shared__ float Wb[DD * DD];
    for (int i = threadIdx.x; i < DD * DD; i += 512) { Wa[i] = W1[i]; Wb[i] = W3[i]; }
    __syncthreads();
    int wid = threadIdx.x >> 6, lane = threadIdx.x & 63;
    int sub = lane & 15, grp = lane >> 4;
    const uint2* xq = (const uint2*)x;
    const unsigned int* cu = (const unsigned int*)cbuf;
    int rbase = blockIdx.x * ROWS_PB + wid * 8;
    for (int rr = 0; rr < 8; rr++) {
        int r = rbase + rr;
        if (r >= nrows) break;
        int e0 = rp[r], e1 = rp[r + 1];
        float a0 = 0.f, a1 = 0.f;
        for (int e = e0; e < e1; e += 4) {
            int idx = e + grp;
            if (idx < e1) {
                unsigned int cv = cu[(size_t)idx * 16 + sub];
                float2 cf = __half22float2(*(const __half2*)&cv);
                a0 += cf.x; a1 += cf.y;
            }
        }
        a0 += __shfl_xor(a0, 16, 64); a0 += __shfl_xor(a0, 32, 64);
        a1 += __shfl_xor(a1, 16, 64); a1 += __shfl_xor(a1, 32, 64);
        float2 rc;
        rc.x = (a0 != 0.f) ? 1.f / a0 : 0.f;
        rc.y = (a1 != 0.f) ? 1.f / a1 : 0.f;
        float g0 = 0, g1 = 0, g2 = 0, g3 = 0, t0 = 0, t1 = 0, t2 = 0, t3 = 0;
        float rsacc = 0.f;
        int e = e0;
        for (; e + 8 <= e1; e += 8) {
#pragma unroll
            for (int u = 0; u < 2; u++) {
                int idx = e + 4 * u + grp;
                int cc = col[idx];
                float wg = bw[idx];
                unsigned int cv = cu[(size_t)idx * 16 + sub];
                float2 cf = __half22float2(*(const __half2*)&cv);
                float pd = fmaf(cf.x, rc.x, cf.y * rc.y);
                pd += __shfl_xor(pd, 1, 64); pd += __shfl_xor(pd, 2, 64);
                pd += __shfl_xor(pd, 4, 64); pd += __shfl_xor(pd, 8, 64);
                float wt = pd * (1.0f / KK);
                rsacc += wt;
                uint2 raw = xq[(size_t)cc * 16 + sub];
                float2 xa = __half22float2(*(const __half2*)&raw.x);
                float2 xb = __half22float2(*(const __half2*)&raw.y);
                g0 += wg * xa.x; g1 += wg * xa.y; g2 += wg * xb.x; g3 += wg * xb.y;
                t0 += wt * xa.x; t1 += wt * xa.y; t2 += wt * xb.x; t3 += wt * xb.y;
            }
        }
        for (; e < e1; e += 4) {
            int idx = e + grp;
            if (idx < e1) {
                int cc = col[idx];
                float wg = bw[idx];
                unsigned int cv = cu[(size_t)idx * 16 + sub];
                float2 cf = __half22float2(*(const __half2*)&cv);
                float pd = fmaf(cf.x, rc.x, cf.y * rc.y);
                pd += __shfl_xor(pd, 1, 64); pd += __shfl_xor(pd, 2, 64);
                pd += __shfl_xor(pd, 4, 64); pd += __shfl_xor(pd, 8, 64);
                float wt = pd * (1.0f / KK);
                rsacc += wt;
                uint2 raw = xq[(size_t)cc * 16 + sub];
                float2 xa = __half22float2(*(const __half2*)&raw.x);
                float2 xb = __half22float2(*(const __half2*)&raw.y);
                g0 += wg * xa.x; g1 += wg * xa.y; g2 += wg * xb.x; g3 += wg * xb.y;
                t0 += wt * xa.x; t1 += wt * xa.y; t2 += wt * xb.x; t3 += wt * xb.y;
            }
        }
#pragma unroll
        for (int off = 16; off <= 32; off <<= 1) {
            g0 += __shfl_xor(g0, off, 64); g1 += __shfl_xor(g1, off, 64);
            g2 += __shfl_xor(g2, off, 64); g3 += __shfl_xor(g3, off, 64);
            t0 += __shfl_xor(t0, off, 64); t1 += __shfl_xor(t1, off, 64);
            t2 += __shfl_xor(t2, off, 64); t3 += __shfl_xor(t3, off, 64);
            rsacc += __shfl_xor(rsacc, off, 64);
        }
        float rsv = (rsacc != 0.f) ? 1.0f / rsacc : 0.f;
        t0 *= rsv; t1 *= rsv; t2 *= rsv; t3 *= rsv;
        float ss = t0 * t0 + t1 * t1 + t2 * t2 + t3 * t3;
        ss += __shfl_xor(ss, 1, 64); ss += __shfl_xor(ss, 2, 64);
        ss += __shfl_xor(ss, 4, 64); ss += __shfl_xor(ss, 8, 64);
        float inv_n = 1.0f / fmaxf(sqrtf(ss), 1e-12f);
        t0 *= inv_n; t1 *= inv_n; t2 *= inv_n; t3 *= inv_n;
        uint2 gp2 = ((const uint2*)(gs + (size_t)r * DD))[sub];
        uint2 tp2 = ((const uint2*)(ts + (size_t)r * DD))[sub];
        float2 gpa = __half22float2(*(const __half2*)&gp2.x);
        float2 gpb = __half22float2(*(const __half2*)&gp2.y);
        float2 tpa = __half22float2(*(const __half2*)&tp2.x);
        float2 tpb = __half22float2(*(const __half2*)&tp2.y);
        float gf0 = gpa.x + g0, gf1 = gpa.y + g1, gf2 = gpb.x + g2, gf3 = gpb.y + g3;
        float tf0 = tpa.x + t0, tf1 = tpa.y + t1, tf2 = tpb.x + t2, tf3 = tpb.y + t3;
        size_t oi = (size_t)r * DD + lane;
        float zv = zp[oi];
#pragma unroll
        for (int l = 0; l < DD; l++) {
            float gl = PRD(gf0, gf1, gf2, gf3, l);
            float tl = PRD(tf0, tf1, tf2, tf3, l);
            zv += gl * Wa[l * DD + lane] + tl * Wb[l * DD + lane];
        }
        float ga0 = __shfl(gf0, lane >> 2, 64), ga1 = __shfl(gf1, lane >> 2, 64);
        float ga2 = __shfl(gf2, lane >> 2, 64), ga3 = __shfl(gf3, lane >> 2, 64);
        float ta0 = __shfl(tf0, lane >> 2, 64), ta1 = __shfl(tf1, lane >> 2, 64);
        float ta2 = __shfl(tf2, lane >> 2, 64), ta3 = __shfl(tf3, lane >> 2, 64);
        int j = lane & 3;
        float gfin = j == 0 ? ga0 : j == 1 ? ga1 : j == 2 ? ga2 : ga3;
        float tfin = j == 0 ? ta0 : j == 1 ? ta1 : j == 2 ? ta2 : ta3;
        float gate = 1.0f / (1.0f + __expf(-zv));
        float xn = gate * gfin + (1.0f - gate) * tfin;
        xh_out[oi] = __float2half(xn);
        acc[oi] += xn;
    }
}

// ---------------- host launcher ----------------

extern "C" void kernel_launch(void* const* d_in, const int* in_sizes, int n_in,
                              void* d_out, int out_size, void* d_ws, size_t ws_size,
                              hipStream_t stream) {
    const float* user_emb = (const float*)d_in[0];
    const float* item_emb = (const float*)d_in[1];
    const float* intents  = (const float*)d_in[2];
    const float* W2       = (const float*)d_in[3];
    const float* b2       = (const float*)d_in[4];
    const float* uu_w     = (const float*)d_in[5];
    const float* ii_w     = (const float*)d_in[6];
    const int*   ui_u     = (const int*)d_in[7];
    const int*   ui_i     = (const int*)d_in[8];
    const int*   uu_h     = (const int*)d_in[9];
    const int*   uu_t     = (const int*)d_in[10];
    const int*   ii_h     = (const int*)d_in[11];
    const int*   ii_t     = (const int*)d_in[12];
    float* acc = (float*)d_out;

    char* pw = (char*)d_ws;
    auto allocb = [&](size_t nbytes) -> char* {
        char* r = pw;
        pw += (nbytes + 255) & ~(size_t)255;
        return r;
    };
    // ~219 MB total
    __half* gs   = (__half*)allocb((size_t)NN * DD * 2);
    __half* ts   = (__half*)allocb((size_t)NN * DD * 2);
    float* zp    = (float*)allocb((size_t)NN * DD * 4);
    __half* xh0  = (__half*)allocb((size_t)NN * DD * 2);
    __half* xh1  = (__half*)allocb((size_t)NN * DD * 2);
    __half* c    = (__half*)allocb((size_t)EUI * KK * 2);  // 64 MB; build scratch aliases here
    float* dinv  = (float*)allocb((size_t)NN * 4);
    float* iuu   = (float*)allocb((size_t)NU * 4);
    float* iii   = (float*)allocb((size_t)NI * 4);
    float* Wd_g  = (float*)allocb((size_t)DD * DD * 4);
    float* Wd_t  = (float*)allocb((size_t)DD * DD * 4);
    int* rp_u    = (int*)allocb(((size_t)NU + 1) * 4);
    int* rp_i    = (int*)allocb(((size_t)NI + 1) * 4);
    int* rp_uu   = (int*)allocb(((size_t)NU + 1) * 4);
    int* rp_ii   = (int*)allocb(((size_t)NI + 1) * 4);
    int* rp_ui   = (int*)allocb(((size_t)NN + 1) * 4);
    int* rp_s    = (int*)allocb(((size_t)NN + 1) * 4);
    int* headU   = (int*)allocb((size_t)EUI * 4);
    int* colUI   = (int*)allocb((size_t)2 * EUI * 4);
    int* head_s  = (int*)allocb((size_t)(EUU + EII) * 4);
    int* col_s   = (int*)allocb((size_t)(EUU + EII) * 4);
    float* bw_s  = (float*)allocb((size_t)(EUU + EII) * 4);
    int* mUI     = (int*)allocb((size_t)EUI * 4);
    float* gwUI  = (float*)allocb((size_t)2 * EUI * 4);

    char* ca = (char*)c;
    int* cur    = (int*)ca;  ca += ((size_t)NU * 4 + 255) & ~(size_t)255;
    int* lst_u  = (int*)ca;  ca += ((size_t)EUI * 4 + 255) & ~(size_t)255;
    int* lst_i  = (int*)ca;  ca += ((size_t)EUI * 4 + 255) & ~(size_t)255;
    int* lst_uu = (int*)ca;  ca += ((size_t)EUU * 4 + 255) & ~(size_t)255;
    int* lst_ii = (int*)ca;  ca += ((size_t)EII * 4 + 255) & ~(size_t)255;
    int* posU   = (int*)ca;

    const int B = 256;

    auto build_csr = [&](const int* h, int E, int n, int* rp, int* lst) {
        hipMemsetAsync(cur, 0, (size_t)n * 4, stream);
        k_count<<<cdiv(E, B), B, 0, stream>>>(h, cur, E);
        k_scan<<<1, 1024, 0, stream>>>(cur, rp, n);
        hipMemsetAsync(cur, 0, (size_t)n * 4, stream);
        k_scatter<<<cdiv(E, B), B, 0, stream>>>(h, rp, cur, lst, E);
    };

    build_csr(ui_u, EUI, NU, rp_u, lst_u);
    build_csr(ui_i, EUI, NI, rp_i, lst_i);
    build_csr(uu_h, EUU, NU, rp_uu, lst_uu);
    build_csr(ii_h, EII, NI, rp_ii, lst_ii);
    k_dinv<<<cdiv(NN, B), B, 0, stream>>>(rp_u, rp_i, dinv);
    k_rowsum_inv<<<cdiv(NU, B), B, 0, stream>>>(rp_uu, lst_uu, uu_w, iuu, NU);
    k_rowsum_inv<<<cdiv(NI, B), B, 0, stream>>>(rp_ii, lst_ii, ii_w, iii, NI);
    k_build_rp2<<<cdiv(NN + 1, B), B, 0, stream>>>(rp_u, rp_i, rp_uu, rp_ii, rp_ui, rp_s);
    k_build_ui<<<cdiv(EUI, B), B, 0, stream>>>(lst_u, ui_u, ui_i, headU, colUI, EUI);
    k_build_colI<<<cdiv(EUI, B), B, 0, stream>>>(lst_i, ui_u, colUI, EUI);
    k_posU<<<cdiv(EUI, B), B, 0, stream>>>(lst_u, posU, EUI);
    k_mapUI<<<cdiv(EUI, B), B, 0, stream>>>(lst_i, posU, mUI, EUI);
    k_build_s<<<cdiv(EUU, B), B, 0, stream>>>(lst_uu, uu_h, uu_t, uu_w, iuu, 0, 0,
                                              head_s, col_s, bw_s, EUU);
    k_build_s<<<cdiv(EII, B), B, 0, stream>>>(lst_ii, ii_h, ii_t, ii_w, iii, NU, EUU,
                                              head_s, col_s, bw_s, EII);
    k_build_gw<<<cdiv(NN, B), B, 0, stream>>>(rp_ui, colUI, dinv, gwUI, NN);
    k_wdiff<<<cdiv(DD * DD, B), B, 0, stream>>>(W2, Wd_g, Wd_t);
    k_init<<<cdiv((long)NN * DD, B), B, 0, stream>>>(user_emb, item_emb, xh0, acc);

    for (int layer = 0; layer < 2; ++layer) {
        const __half* xin = (layer == 0) ? xh0 : xh1;
        __half* xout = (layer == 0) ? xh1 : xh0;

        // ---- UI phase (2 dispatches) ----
        k_passA<<<1024, B, 0, stream>>>(headU, colUI, xin, intents, c, EUI);
        k_fused_ui<<<cdiv(NN, ROWS_PB), 512, 0, stream>>>(rp_ui, colUI, gwUI, c, mUI,
                                                          Wd_g, Wd_t, b2, xin, gs, ts, zp, NN);

        // ---- UU+II phase (2 dispatches) ----
        k_passA<<<1024, B, 0, stream>>>(head_s, col_s, xin, intents, c, EUU + EII);
        k_fused_fin<<<cdiv(NN, ROWS_PB), 512, 0, stream>>>(rp_s, col_s, bw_s, c,
                                                           W2 + DD * DD, W2 + 3 * DD * DD,
                                                           xin, gs, ts, zp, xout, acc, NN);
    }
}